// Round 9
// baseline (16847.327 us; speedup 1.0000x reference)
//
#include <hip/hip_runtime.h>
#include <cstdint>
#include <cstddef>

typedef unsigned short u16;
typedef unsigned int   u32;

#define S_LEN 100
#define B_SZ  512
#define H_LS  300
#define NHOP  3
#define NC_   7
#define BM1   511   // B-1

__device__ __forceinline__ float u2f(u16 u) {
  union { u32 i; float f; } x; x.i = ((u32)u) << 16; return x.f;
}
__device__ __forceinline__ float sigm(float x) { return 1.0f / (1.0f + expf(-x)); }

// ------------------------------------------------------------------
// dtype detect on emb raw bits (validated r1->r2)
// ------------------------------------------------------------------
__global__ void detect_k(const u32* __restrict__ raw, int* __restrict__ flag) {
  __shared__ int cnt;
  if (threadIdx.x == 0) cnt = 0;
  __syncthreads();
  u32 w = raw[threadIdx.x];
  u32 lo = w & 0xFFFFu;
  int e = (int)((lo >> 7) & 0xFF);
  int pl = (lo == 0u || (e >= 0x70 && e <= 0x8E)) ? 1 : 0;
  atomicAdd(&cnt, pl);
  __syncthreads();
  if (threadIdx.x == 0) *flag = (cnt >= 192) ? 1 : 0;   // 1 = bf16 device data
}

// ------------------------------------------------------------------
// normalize ALL float params -> f32 mirror allf (validated r6/r7)
// ------------------------------------------------------------------
#define NF_NSEG 28
#define NF_TOT  1748007
struct NormFArgs { const void* src[NF_NSEG]; const int* flag; float* dst; };

__global__ __launch_bounds__(256) void norm_f32(NormFArgs a) {
  const int P[NF_NSEG + 1] = {
    0,360000,720000,1080000,1440000,1441200,1442400,1443600,
    1444800,1474800,1504800,1505100,1505400,1535400,1565400,1565700,
    1566000,1626000,1626100,1656100,1686100,1716100,1746100,1746400,
    1746700,1747000,1747300,1748000,1748007};
  int fl = *a.flag;
  int stride = gridDim.x * 256;
  for (int i = blockIdx.x * 256 + threadIdx.x; i < NF_TOT; i += stride) {
    int s = 0;
    while (i >= P[s + 1]) ++s;
    int k = i - P[s];
    float v = fl ? u2f(((const u16*)a.src[s])[k]) : ((const float*)a.src[s])[k];
    a.dst[i] = v;
  }
}
#define AF_LWIH_F 0
#define AF_LWHH_F 360000
#define AF_LWIH_B 720000
#define AF_LWHH_B 1080000
#define AF_LBIH_F 1440000
#define AF_LBHH_F 1441200
#define AF_LBIH_B 1442400
#define AF_LBHH_B 1443600
#define AF_GWIH_F 1444800
#define AF_GWHH_F 1474800
#define AF_GBIH_F 1504800
#define AF_GBHH_F 1505100
#define AF_GWIH_B 1505400
#define AF_GWHH_B 1535400
#define AF_GBIH_B 1565400
#define AF_GBHH_B 1565700
#define AF_LIN1W  1566000
#define AF_LIN1B  1626000
#define AF_ATTWR  1626100
#define AF_ATTUR  1656100
#define AF_ATTW   1686100
#define AF_ATTU   1716100
#define AF_ATTBR  1746100
#define AF_ATTBUR 1746400
#define AF_ATTBW  1746700
#define AF_ATTBU  1747000
#define AF_CLSW   1747300
#define AF_CLSB   1748000

// ------------------------------------------------------------------
// transpose 100x100 chunks to k-major: gWhh (2x3) + att Ur/U (3 hops x2)
// ------------------------------------------------------------------
__global__ void transp_k(const float* __restrict__ allf, float* __restrict__ wt) {
  int idx = blockIdx.x * 256 + threadIdx.x;
  if (idx >= 120000) return;
  int seg = idx / 10000;
  int rem = idx - seg * 10000;
  int k = rem / 100, j = rem - (rem / 100) * 100;
  int srcbase;
  if (seg < 3)      srcbase = AF_GWHH_F + seg * 10000;
  else if (seg < 6) srcbase = AF_GWHH_B + (seg - 3) * 10000;
  else if (seg < 9) srcbase = AF_ATTUR + (seg - 6) * 10000;
  else              srcbase = AF_ATTU  + (seg - 9) * 10000;
  wt[seg * 10000 + k * 100 + j] = allf[srcbase + j * 100 + k];
}

// ------------------------------------------------------------------
// LSTM weights -> k-major: wLT[dir][k][g*300+j], k in [0,600)
// (k<300: Wih col k; k>=300: Whh col k-300).  Plus bias sums bsum[dir][1200].
// ------------------------------------------------------------------
__global__ void tr_lstm(const float* __restrict__ allf, float* __restrict__ wLT,
                        float* __restrict__ bsum) {
  int idx = blockIdx.x * 256 + threadIdx.x;
  if (idx < 1440000) {
    int dir = idx / 720000;
    int rem = idx - dir * 720000;
    int k = rem / 1200, gj = rem - (rem / 1200) * 1200;
    int src;
    if (k < 300) src = (dir ? AF_LWIH_B : AF_LWIH_F) + gj * 300 + k;
    else         src = (dir ? AF_LWHH_B : AF_LWHH_F) + gj * 300 + (k - 300);
    wLT[idx] = allf[src];
  } else if (idx < 1442400) {
    int i2 = idx - 1440000;
    int dir = i2 / 1200, gj = i2 - (i2 / 1200) * 1200;
    bsum[i2] = allf[(dir ? AF_LBIH_B : AF_LBIH_F) + gj]
             + allf[(dir ? AF_LBHH_B : AF_LBHH_F) + gj];
  }
}

// ------------------------------------------------------------------
// LSTM step v4: grid (16 rowt[32], 10 jt[32], 2 dir), 256 thr.
// Thread (q=tid%8, rg=tid/8) owns j-quad jbase=j0+q*4 x 1 row rg.
// Weights k-major -> float4 loads contiguous across q-lanes.
// x (emb|h) combined in LDS xs[32][604] (pad 604 -> conflict-free bcast).
// ------------------------------------------------------------------
struct Lstm4Args {
  const int* sents; const int* lens;
  const void* emb;
  const float* wLT; const float* bsum;
  const int* flag;
  float* h;      // [parity][dir][512][300]
  float* c;      // [dir][512][300]
  float* maxb;   // [512][600]
  int s;
};

__global__ __launch_bounds__(256) void lstm4(Lstm4Args a) {
  __shared__ float xs[32][604];      // [row][k]: k<300 emb, k>=300 h_{t-1}
  const int tid = threadIdx.x;
  const int r0  = blockIdx.x * 32;
  const int j0  = blockIdx.y * 32;
  const int dir = blockIdx.z;
  const int s   = a.s;
  const int tt  = dir ? (S_LEN - 1 - s) : s;
  const int rp  = s & 1;
  const float* hread  = a.h + (size_t)(rp * 2 + dir) * B_SZ * H_LS;
  float*       hwrite = a.h + (size_t)((1 - rp) * 2 + dir) * B_SZ * H_LS;
  const int fl = *a.flag;

  for (int idx = tid; idx < 32 * 300; idx += 256) {
    int r = idx / 300, k = idx - r * 300;
    int tok = a.sents[(r0 + r) * S_LEN + tt];
    xs[r][k] = fl ? u2f(((const u16*)a.emb)[(size_t)tok * 300 + k])
                  : ((const float*)a.emb)[(size_t)tok * 300 + k];
    xs[r][300 + k] = (s > 0) ? hread[(size_t)(r0 + r) * H_LS + k] : 0.f;
  }
  __syncthreads();

  const int q  = tid & 7;
  const int rg = tid >> 3;          // 0..31, the row this thread owns
  const int jbase = j0 + q * 4;
  if (jbase < 300) {
    float4 a0 = {0,0,0,0}, a1 = {0,0,0,0}, a2 = {0,0,0,0}, a3 = {0,0,0,0};
    const float* wp = a.wLT + (size_t)dir * 720000 + jbase;
    const float* xrow = xs[rg];
    for (int k = 0; k < 600; ++k) {
      float xv = xrow[k];
      const float* wk = wp + k * 1200;
      float4 w0 = *(const float4*)(wk);
      float4 w1 = *(const float4*)(wk + 300);
      float4 w2 = *(const float4*)(wk + 600);
      float4 w3 = *(const float4*)(wk + 900);
      a0.x += xv * w0.x; a0.y += xv * w0.y; a0.z += xv * w0.z; a0.w += xv * w0.w;
      a1.x += xv * w1.x; a1.y += xv * w1.y; a1.z += xv * w1.z; a1.w += xv * w1.w;
      a2.x += xv * w2.x; a2.y += xv * w2.y; a2.z += xv * w2.z; a2.w += xv * w2.w;
      a3.x += xv * w3.x; a3.y += xv * w3.y; a3.z += xv * w3.z; a3.w += xv * w3.w;
    }
    const float* bs = a.bsum + dir * 1200;
    float4 b0 = *(const float4*)(bs + jbase);
    float4 b1 = *(const float4*)(bs + 300 + jbase);
    float4 b2 = *(const float4*)(bs + 600 + jbase);
    float4 b3 = *(const float4*)(bs + 900 + jbase);
    float gi[4] = {a0.x + b0.x, a0.y + b0.y, a0.z + b0.z, a0.w + b0.w};
    float gf[4] = {a1.x + b1.x, a1.y + b1.y, a1.z + b1.z, a1.w + b1.w};
    float gg[4] = {a2.x + b2.x, a2.y + b2.y, a2.z + b2.z, a2.w + b2.w};
    float go[4] = {a3.x + b3.x, a3.y + b3.y, a3.z + b3.z, a3.w + b3.w};

    const int b = r0 + rg;
    const bool m = tt < a.lens[b];
    float* cptr = a.c + ((size_t)dir * B_SZ + b) * H_LS + jbase;
    float* hptr = hwrite + (size_t)b * H_LS + jbase;
    float* mptr = a.maxb + (size_t)b * 600 + dir * 300 + jbase;
    float hv[4], ov[4];
    if (m) {
      float4 cp = (s == 0) ? make_float4(0, 0, 0, 0) : *(const float4*)cptr;
      float cpv[4] = {cp.x, cp.y, cp.z, cp.w};
      float cn[4];
      #pragma unroll
      for (int jj = 0; jj < 4; ++jj) {
        cn[jj] = sigm(gf[jj]) * cpv[jj] + sigm(gi[jj]) * tanhf(gg[jj]);
        hv[jj] = sigm(go[jj]) * tanhf(cn[jj]);
        ov[jj] = hv[jj];
      }
      *(float4*)cptr = make_float4(cn[0], cn[1], cn[2], cn[3]);
    } else {
      #pragma unroll
      for (int jj = 0; jj < 4; ++jj) {
        hv[jj] = (s == 0) ? 0.f : xs[rg][300 + jbase + jj];
        ov[jj] = 0.f;
      }
      if (s == 0) *(float4*)cptr = make_float4(0, 0, 0, 0);
    }
    *(float4*)hptr = make_float4(hv[0], hv[1], hv[2], hv[3]);
    if (s == 0) {
      *(float4*)mptr = make_float4(ov[0], ov[1], ov[2], ov[3]);
    } else {
      float4 mo = *(const float4*)mptr;
      mo.x = fmaxf(mo.x, ov[0]); mo.y = fmaxf(mo.y, ov[1]);
      mo.z = fmaxf(mo.z, ov[2]); mo.w = fmaxf(mo.w, ov[3]);
      *(float4*)mptr = mo;
    }
  }
}

// ------------------------------------------------------------------
// s_utt = tanh(maxpl @ lin1_W^T + lin1_b)   [512,100]
// ------------------------------------------------------------------
__global__ __launch_bounds__(128) void sutt_k(const float* __restrict__ maxb,
                                              const float* __restrict__ W,
                                              const float* __restrict__ bb,
                                              float* __restrict__ sutt) {
  int b = blockIdx.x, tid = threadIdx.x;
  __shared__ float mx[600];
  for (int i = tid; i < 600; i += 128) mx[i] = maxb[b * 600 + i];
  __syncthreads();
  if (tid < 100) {
    float acc = bb[tid];
    const float* wr = W + tid * 600;
    for (int k = 0; k < 600; ++k) acc += mx[k] * wr[k];
    sutt[b * 100 + tid] = tanhf(acc);
  }
}

// ------------------------------------------------------------------
// GRU x-projection: xg[dir][t][row][300] f32 (incl. bih)
// ------------------------------------------------------------------
__global__ __launch_bounds__(256) void gxg3(const float* __restrict__ sutt,
                                            const float* __restrict__ Wf, const float* __restrict__ bf_,
                                            const float* __restrict__ Wb, const float* __restrict__ bb_,
                                            float* __restrict__ xg) {
  __shared__ float bts[32][101];
  int tid = threadIdx.x;
  int rt = blockIdx.x * 32, t = blockIdx.y, dir = blockIdx.z;
  int tin = dir ? (39 - t) : t;
  for (int idx = tid; idx < 3200; idx += 256) {
    int r = idx / 100, k = idx - r * 100, row = rt + r;
    float v = 0.f;
    if (row < BM1) {
      int srow = row + 1 - 40 + tin;
      if (srow >= 0) v = sutt[srow * 100 + k];
    }
    bts[r][k] = v;
  }
  __syncthreads();
  const float* Wm = dir ? Wb : Wf;
  const float* bm = dir ? bb_ : bf_;
  for (int o = tid; o < 9600; o += 256) {
    int r = o & 31, g = o >> 5;
    float acc = bm[g];
    const float* wr = Wm + g * 100;
    const float* br = bts[r];
    for (int k = 0; k < 100; ++k) acc += br[k] * wr[k];
    int row = rt + r;
    if (row < BM1) xg[(((size_t)dir * 40 + t) * BM1 + row) * 300 + g] = acc;
  }
}

// ------------------------------------------------------------------
// GRU scan v4: 512 thr, 1 (row,j)/thread, register-h, ping-pong LDS,
// one barrier/step, xg prefetch. Grid (128, 2).
// ------------------------------------------------------------------
struct Gru4Args {
  const float* wt;          // gWhhT at + dir*30000
  const float* bhh[2];
  const float* xg;
  float* memf; float* memb;
};

__global__ __launch_bounds__(512) void gru4(Gru4Args a) {
  __shared__ float WT[30000];    // [3][100 k][100 j]
  __shared__ float hl[2][4][104];
  int tid = threadIdx.x, rt = blockIdx.x * 4, dir = blockIdx.y;
  const float* src = a.wt + dir * 30000;
  for (int i = tid; i < 30000; i += 512) WT[i] = src[i];
  for (int i = tid; i < 832; i += 512) ((float*)hl)[i] = 0.f;
  int r = tid / 100, j = tid - r * 100;
  int row = rt + r;
  bool act = (tid < 400) && (row < BM1);
  const float* bhh = a.bhh[dir];
  float xr = 0.f, xz = 0.f, xn = 0.f;
  if (act) {
    size_t xb = ((size_t)(dir * 40) * BM1 + row) * 300;
    xr = a.xg[xb + j]; xz = a.xg[xb + 100 + j]; xn = a.xg[xb + 200 + j];
  }
  float hprev = 0.f;
  __syncthreads();
  for (int t = 0; t < 40; ++t) {
    int nxt = (t + 1) & 1, cur = t & 1;
    float xr2 = 0.f, xz2 = 0.f, xn2 = 0.f;
    if (act && t < 39) {
      size_t xb = ((size_t)(dir * 40 + t + 1) * BM1 + row) * 300;
      xr2 = a.xg[xb + j]; xz2 = a.xg[xb + 100 + j]; xn2 = a.xg[xb + 200 + j];
    }
    float v = 0.f;
    if (act) {
      float hr = bhh[j], hz = bhh[100 + j], hn = bhh[200 + j];
      const float* w0 = WT + j;
      const float* hrow = hl[cur][r];
      for (int k = 0; k < 100; ++k) {
        float hv = hrow[k];
        hr += hv * w0[k * 100];
        hz += hv * w0[10000 + k * 100];
        hn += hv * w0[20000 + k * 100];
      }
      float rg_ = sigm(xr + hr), zg = sigm(xz + hz);
      float ng = tanhf(xn + rg_ * hn);
      v = (1.f - zg) * ng + zg * hprev;
      int tin = dir ? (39 - t) : t;
      (dir ? a.memb : a.memf)[((size_t)tin * BM1 + row) * 100 + j] = v;
    }
    if (tid < 400) hl[nxt][r][j] = v;
    hprev = v;
    __syncthreads();
    xr = xr2; xz = xz2; xn = xn2;
  }
}

// mem = bt + mem_f + mem_b
__global__ void memcomb(const float* __restrict__ memf, const float* __restrict__ memb,
                        const float* __restrict__ sutt, float* __restrict__ memm) {
  int idx = blockIdx.x * 256 + threadIdx.x;
  if (idx >= 40 * BM1 * 100) return;
  int j = idx % 100; int rem = idx / 100; int row = rem % BM1; int t = rem / BM1;
  float v = memf[idx] + memb[idx];
  int sidx = row + 1 - 40 + t;
  if (sidx >= 0) v += sutt[sidx * 100 + j];
  memm[idx] = v;
}

__global__ void epsinit(const float* __restrict__ sutt, float* __restrict__ eps) {
  int idx = blockIdx.x * 256 + threadIdx.x;
  if (idx < BM1 * 100) eps[idx] = sutt[idx + 100];
}

// attention scores + softmax -> gates + attn output (f32)
__global__ __launch_bounds__(64) void attnsc(const float* __restrict__ eps,
                                             const float* __restrict__ memm,
                                             float* __restrict__ gatesw,
                                             float* __restrict__ outat) {
  int row = blockIdx.x, k = threadIdx.x;
  __shared__ float el[100];
  for (int i = k; i < 100; i += 64) el[i] = eps[row * 100 + i];
  __syncthreads();
  float val = -INFINITY;
  if (k < 40) {
    if (row + 1 - 40 + k >= 0) {
      const float* mrow = memm + ((size_t)k * BM1 + row) * 100;
      float s = 0.f;
      for (int d = 0; d < 100; ++d) s += el[d] * mrow[d];
      val = s;
    } else val = -1e10f;
  }
  float mx = val;
  for (int off = 32; off > 0; off >>= 1) mx = fmaxf(mx, __shfl_xor(mx, off));
  float ex = (k < 40) ? expf(val - mx) : 0.f;
  float sm = ex;
  for (int off = 32; off > 0; off >>= 1) sm += __shfl_xor(sm, off);
  if (k < 40) {
    float sc = ex / sm;
    gatesw[k * BM1 + row] = sc;
    outat[row * 40 + k] = sc;
  }
}

// cr/cw precompute GEMM: grid (16, 40, 2)
__global__ __launch_bounds__(256) void crcw3(const float* __restrict__ memm,
                                             const float* __restrict__ Wr, const float* __restrict__ br,
                                             const float* __restrict__ Ww, const float* __restrict__ bw,
                                             float* __restrict__ crb, float* __restrict__ cwb) {
  __shared__ float ml[32][101];
  int tid = threadIdx.x;
  int rt = blockIdx.x * 32, t = blockIdx.y, which = blockIdx.z;
  for (int idx = tid; idx < 3200; idx += 256) {
    int r = idx / 100, k = idx - r * 100; int row = rt + r;
    ml[r][k] = (row < BM1) ? memm[((size_t)t * BM1 + row) * 100 + k] : 0.f;
  }
  __syncthreads();
  const float* Wm = which ? Ww : Wr;
  const float* bm = which ? bw : br;
  float* ob = which ? cwb : crb;
  for (int o = tid; o < 3200; o += 256) {
    int r = o & 31, hh = o >> 5;
    float acc = bm[hh];
    const float* wr = Wm + hh * 100;
    for (int k = 0; k < 100; ++k) acc += ml[r][k] * wr[k];
    int row = rt + r;
    if (row < BM1) ob[((size_t)t * BM1 + row) * 100 + hh] = acc;
  }
}

// ------------------------------------------------------------------
// AttnGRU scan v4: 512 thr, 4 rows/block, register-h, ping-pong,
// cr/cw/gate prefetch. Grid 128.
// ------------------------------------------------------------------
struct Att4Args {
  const float* urT; const float* uT;
  const float* bur; const float* bu;
  const float* crb; const float* cwb;
  const float* gatesw; float* eps;
};

__global__ __launch_bounds__(512) void attscan4(Att4Args a) {
  __shared__ float UrT[10000];
  __shared__ float UT[10000];
  __shared__ float hl[2][4][104];
  int tid = threadIdx.x, rt = blockIdx.x * 4;
  for (int i = tid; i < 10000; i += 512) { UrT[i] = a.urT[i]; UT[i] = a.uT[i]; }
  for (int i = tid; i < 832; i += 512) ((float*)hl)[i] = 0.f;
  int r = tid / 100, j = tid - r * 100;
  int row = rt + r;
  bool act = (tid < 400) && (row < BM1);
  float cr = 0.f, cw = 0.f, gw = 0.f;
  if (act) {
    size_t ix = (size_t)row * 100 + j;
    cr = a.crb[ix]; cw = a.cwb[ix]; gw = a.gatesw[row];
  }
  float hprev = 0.f;
  __syncthreads();
  for (int t = 0; t < 40; ++t) {
    int nxt = (t + 1) & 1, cur = t & 1;
    float cr2 = 0.f, cw2 = 0.f, gw2 = 0.f;
    if (act && t < 39) {
      size_t ix = ((size_t)(t + 1) * BM1 + row) * 100 + j;
      cr2 = a.crb[ix]; cw2 = a.cwb[ix]; gw2 = a.gatesw[(t + 1) * BM1 + row];
    }
    float v = 0.f;
    if (act) {
      float hr = a.bur[j], hu = a.bu[j];
      const float* hrow = hl[cur][r];
      for (int k = 0; k < 100; ++k) {
        float hv = hrow[k];
        hr += hv * UrT[k * 100 + j];
        hu += hv * UT[k * 100 + j];
      }
      float rg_ = sigm(cr + hr);
      float ht = tanhf(cw + rg_ * hu);
      v = gw * ht + (1.f - gw) * hprev;
    }
    if (tid < 400) hl[nxt][r][j] = v;
    hprev = v;
    __syncthreads();
    cr = cr2; cw = cw2; gw = gw2;
  }
  if (act) a.eps[(size_t)row * 100 + j] += hprev;
}

// classifier -> f32
__global__ __launch_bounds__(64) void cls_k(const float* __restrict__ sutt,
                                            const float* __restrict__ eps,
                                            const float* __restrict__ cW, const float* __restrict__ cb,
                                            float* __restrict__ outp) {
  int b = blockIdx.x, j = threadIdx.x;
  __shared__ float sl[100];
  for (int i = j; i < 100; i += 64) sl[i] = (b == 0) ? sutt[i] : eps[(b - 1) * 100 + i];
  __syncthreads();
  float lg = -INFINITY;
  if (j < 7) {
    lg = cb[j];
    const float* wr = cW + j * 100;
    for (int k = 0; k < 100; ++k) lg += sl[k] * wr[k];
  }
  float mx = lg;
  for (int off = 32; off > 0; off >>= 1) mx = fmaxf(mx, __shfl_xor(mx, off));
  float ex = (j < 7) ? expf(lg - mx) : 0.f;
  float sm = ex;
  for (int off = 32; off > 0; off >>= 1) sm += __shfl_xor(sm, off);
  if (j < 7) outp[b * 7 + j] = lg - mx - logf(sm);
}

// ------------------------------------------------------------------
extern "C" void kernel_launch(void* const* d_in, const int* in_sizes, int n_in,
                              void* d_out, int out_size, void* d_ws, size_t ws_size,
                              hipStream_t stream) {
  (void)n_in; (void)out_size; (void)ws_size;

  bool sigOrder = (in_sizes[7] == 360000);   // r4 evidence: dict order

  const void *p_sents, *p_lens, *p_emb;
  const void *p_lWih_f, *p_lWhh_f, *p_lbih_f, *p_lbhh_f;
  const void *p_lWih_b, *p_lWhh_b, *p_lbih_b, *p_lbhh_b;
  const void *p_gWih_f, *p_gWhh_f, *p_gbih_f, *p_gbhh_f;
  const void *p_gWih_b, *p_gWhh_b, *p_gbih_b, *p_gbhh_b;
  const void *p_lin1W, *p_lin1b;
  const void *p_attWr, *p_attUr, *p_attW, *p_attU;
  const void *p_attbr, *p_attbur, *p_attbw, *p_attbu;
  const void *p_clsW, *p_clsb;

  p_sents = d_in[0]; p_lens = d_in[1]; p_emb = d_in[2];
  p_lWih_f = d_in[3]; p_lWhh_f = d_in[4]; p_lbih_f = d_in[5]; p_lbhh_f = d_in[6];
  if (sigOrder) {
    p_lWih_b = d_in[7];  p_lWhh_b = d_in[8];  p_lbih_b = d_in[9];  p_lbhh_b = d_in[10];
    p_lin1W  = d_in[11]; p_lin1b  = d_in[12];
    p_gWih_f = d_in[13]; p_gWhh_f = d_in[14]; p_gbih_f = d_in[15]; p_gbhh_f = d_in[16];
    p_gWih_b = d_in[17]; p_gWhh_b = d_in[18]; p_gbih_b = d_in[19]; p_gbhh_b = d_in[20];
    p_attWr  = d_in[21]; p_attbr  = d_in[22]; p_attUr  = d_in[23]; p_attbur = d_in[24];
    p_attW   = d_in[25]; p_attbw  = d_in[26]; p_attU   = d_in[27]; p_attbu  = d_in[28];
    p_clsW   = d_in[29]; p_clsb   = d_in[30];
  } else {
    p_gWih_f = d_in[7];  p_gWhh_f = d_in[8];  p_gbih_f = d_in[9];  p_gbhh_f = d_in[10];
    p_lWih_b = d_in[11]; p_lWhh_b = d_in[12]; p_lbih_b = d_in[13]; p_lbhh_b = d_in[14];
    p_gWih_b = d_in[15]; p_gWhh_b = d_in[16]; p_gbih_b = d_in[17]; p_gbhh_b = d_in[18];
    p_lin1W  = d_in[19]; p_lin1b  = d_in[20];
    p_attWr  = d_in[21]; p_attUr  = d_in[22]; p_attW   = d_in[23]; p_attU   = d_in[24];
    p_attbr  = d_in[25]; p_attbur = d_in[26]; p_attbw  = d_in[27]; p_attbu  = d_in[28];
    p_clsW   = d_in[29]; p_clsb   = d_in[30];
  }

  char* wp = (char*)d_ws;
  auto carve = [&](size_t bytes) {
    char* p = wp;
    wp += (bytes + 255) & ~(size_t)255;
    return p;
  };
  int*   flag  = (int*)  carve(256);
  float* allf  = (float*)carve((size_t)NF_TOT * 4);
  float* wt    = (float*)carve((size_t)120000 * 4);
  float* wLT   = (float*)carve((size_t)1440000 * 4);
  float* bsum  = (float*)carve((size_t)2400 * 4);
  float* hbuf  = (float*)carve((size_t)2 * 2 * B_SZ * H_LS * 4);
  float* cst   = (float*)carve((size_t)2 * B_SZ * H_LS * 4);
  float* maxb  = (float*)carve((size_t)B_SZ * 600 * 4);
  float* sutt  = (float*)carve((size_t)B_SZ * 100 * 4);
  float* xg    = (float*)carve((size_t)2 * 40 * BM1 * 300 * 4);
  float* memf  = (float*)carve((size_t)40 * BM1 * 100 * 4);
  float* memb  = (float*)carve((size_t)40 * BM1 * 100 * 4);
  float* memm  = (float*)carve((size_t)40 * BM1 * 100 * 4);
  float* gatesw= (float*)carve((size_t)40 * BM1 * 4);
  float* eps   = (float*)carve((size_t)BM1 * 100 * 4);
  // crb/cwb alias into xg (xg dead after gru4; stream-ordered)
  float* crb   = xg;
  float* cwb   = xg + (size_t)40 * BM1 * 100;

  float* out_pred = (float*)d_out;
  float* out_attn = out_pred + (size_t)B_SZ * NC_;

  detect_k<<<1, 256, 0, stream>>>((const u32*)p_emb, flag);

  NormFArgs nf;
  {
    const void* srcs[NF_NSEG] = {
      p_lWih_f, p_lWhh_f, p_lWih_b, p_lWhh_b,
      p_lbih_f, p_lbhh_f, p_lbih_b, p_lbhh_b,
      p_gWih_f, p_gWhh_f, p_gbih_f, p_gbhh_f,
      p_gWih_b, p_gWhh_b, p_gbih_b, p_gbhh_b,
      p_lin1W,  p_lin1b,
      p_attWr,  p_attUr,  p_attW,   p_attU,
      p_attbr,  p_attbur, p_attbw,  p_attbu,
      p_clsW,   p_clsb };
    for (int i = 0; i < NF_NSEG; ++i) nf.src[i] = srcs[i];
    nf.flag = flag; nf.dst = allf;
  }
  norm_f32<<<2048, 256, 0, stream>>>(nf);
  transp_k<<<(120000 + 255) / 256, 256, 0, stream>>>(allf, wt);
  tr_lstm<<<(1442400 + 255) / 256, 256, 0, stream>>>(allf, wLT, bsum);

  Lstm4Args la;
  la.sents = (const int*)p_sents; la.lens = (const int*)p_lens;
  la.emb = p_emb;
  la.wLT = wLT; la.bsum = bsum;
  la.flag = flag;
  la.h = hbuf; la.c = cst; la.maxb = maxb;
  for (int s = 0; s < S_LEN; ++s) {
    la.s = s;
    lstm4<<<dim3(16, 10, 2), 256, 0, stream>>>(la);
  }

  sutt_k<<<512, 128, 0, stream>>>(maxb, allf + AF_LIN1W, allf + AF_LIN1B, sutt);

  gxg3<<<dim3(16, 40, 2), 256, 0, stream>>>(sutt,
      allf + AF_GWIH_F, allf + AF_GBIH_F,
      allf + AF_GWIH_B, allf + AF_GBIH_B, xg);

  Gru4Args ga;
  ga.wt = wt;
  ga.bhh[0] = allf + AF_GBHH_F; ga.bhh[1] = allf + AF_GBHH_B;
  ga.xg = xg; ga.memf = memf; ga.memb = memb;
  gru4<<<dim3(128, 2), 512, 0, stream>>>(ga);

  memcomb<<<(40 * BM1 * 100 + 255) / 256, 256, 0, stream>>>(memf, memb, sutt, memm);
  epsinit<<<(BM1 * 100 + 255) / 256, 256, 0, stream>>>(sutt, eps);

  for (int hop = 0; hop < NHOP; ++hop) {
    attnsc<<<BM1, 64, 0, stream>>>(eps, memm, gatesw, out_attn + (size_t)hop * BM1 * 40);
    crcw3<<<dim3(16, 40, 2), 256, 0, stream>>>(memm,
        allf + AF_ATTWR + hop * 10000, allf + AF_ATTBR + hop * 100,
        allf + AF_ATTW  + hop * 10000, allf + AF_ATTBW + hop * 100, crb, cwb);
    Att4Args aa;
    aa.urT = wt + 60000 + hop * 10000;
    aa.uT  = wt + 90000 + hop * 10000;
    aa.bur = allf + AF_ATTBUR + hop * 100;
    aa.bu  = allf + AF_ATTBU  + hop * 100;
    aa.crb = crb; aa.cwb = cwb;
    aa.gatesw = gatesw; aa.eps = eps;
    attscan4<<<128, 512, 0, stream>>>(aa);
  }

  cls_k<<<512, 64, 0, stream>>>(sutt, eps, allf + AF_CLSW, allf + AF_CLSB, out_pred);
}

// Round 10
// 16680.034 us; speedup vs baseline: 1.0100x; 1.0100x over previous
//
#include <hip/hip_runtime.h>
#include <cstdint>
#include <cstddef>

typedef unsigned short u16;
typedef unsigned int   u32;

#define S_LEN 100
#define B_SZ  512
#define H_LS  300
#define NHOP  3
#define NC_   7
#define BM1   511   // B-1

__device__ __forceinline__ float u2f(u16 u) {
  union { u32 i; float f; } x; x.i = ((u32)u) << 16; return x.f;
}
__device__ __forceinline__ float sigm(float x) { return 1.0f / (1.0f + expf(-x)); }

// ------------------------------------------------------------------
// dtype detect on emb raw bits (validated r1->r2)
// ------------------------------------------------------------------
__global__ void detect_k(const u32* __restrict__ raw, int* __restrict__ flag) {
  __shared__ int cnt;
  if (threadIdx.x == 0) cnt = 0;
  __syncthreads();
  u32 w = raw[threadIdx.x];
  u32 lo = w & 0xFFFFu;
  int e = (int)((lo >> 7) & 0xFF);
  int pl = (lo == 0u || (e >= 0x70 && e <= 0x8E)) ? 1 : 0;
  atomicAdd(&cnt, pl);
  __syncthreads();
  if (threadIdx.x == 0) *flag = (cnt >= 192) ? 1 : 0;   // 1 = bf16 device data
}

// ------------------------------------------------------------------
// normalize ALL float params -> f32 mirror allf (validated r6/r7)
// ------------------------------------------------------------------
#define NF_NSEG 28
#define NF_TOT  1748007
struct NormFArgs { const void* src[NF_NSEG]; const int* flag; float* dst; };

__global__ __launch_bounds__(256) void norm_f32(NormFArgs a) {
  const int P[NF_NSEG + 1] = {
    0,360000,720000,1080000,1440000,1441200,1442400,1443600,
    1444800,1474800,1504800,1505100,1505400,1535400,1565400,1565700,
    1566000,1626000,1626100,1656100,1686100,1716100,1746100,1746400,
    1746700,1747000,1747300,1748000,1748007};
  int fl = *a.flag;
  int stride = gridDim.x * 256;
  for (int i = blockIdx.x * 256 + threadIdx.x; i < NF_TOT; i += stride) {
    int s = 0;
    while (i >= P[s + 1]) ++s;
    int k = i - P[s];
    float v = fl ? u2f(((const u16*)a.src[s])[k]) : ((const float*)a.src[s])[k];
    a.dst[i] = v;
  }
}
#define AF_LWIH_F 0
#define AF_LWHH_F 360000
#define AF_LWIH_B 720000
#define AF_LWHH_B 1080000
#define AF_LBIH_F 1440000
#define AF_LBHH_F 1441200
#define AF_LBIH_B 1442400
#define AF_LBHH_B 1443600
#define AF_GWIH_F 1444800
#define AF_GWHH_F 1474800
#define AF_GBIH_F 1504800
#define AF_GBHH_F 1505100
#define AF_GWIH_B 1505400
#define AF_GWHH_B 1535400
#define AF_GBIH_B 1565400
#define AF_GBHH_B 1565700
#define AF_LIN1W  1566000
#define AF_LIN1B  1626000
#define AF_ATTWR  1626100
#define AF_ATTUR  1656100
#define AF_ATTW   1686100
#define AF_ATTU   1716100
#define AF_ATTBR  1746100
#define AF_ATTBUR 1746400
#define AF_ATTBW  1746700
#define AF_ATTBU  1747000
#define AF_CLSW   1747300
#define AF_CLSB   1748000

// ------------------------------------------------------------------
// transpose 100x100 chunks to k-major: gWhh (2x3) + att Ur/U (3 hops x2)
// ------------------------------------------------------------------
__global__ void transp_k(const float* __restrict__ allf, float* __restrict__ wt) {
  int idx = blockIdx.x * 256 + threadIdx.x;
  if (idx >= 120000) return;
  int seg = idx / 10000;
  int rem = idx - seg * 10000;
  int k = rem / 100, j = rem - (rem / 100) * 100;
  int srcbase;
  if (seg < 3)      srcbase = AF_GWHH_F + seg * 10000;
  else if (seg < 6) srcbase = AF_GWHH_B + (seg - 3) * 10000;
  else if (seg < 9) srcbase = AF_ATTUR + (seg - 6) * 10000;
  else              srcbase = AF_ATTU  + (seg - 9) * 10000;
  wt[seg * 10000 + k * 100 + j] = allf[srcbase + j * 100 + k];
}

// ------------------------------------------------------------------
// LSTM weights -> k-major: wLT[dir][k][g*300+j], k in [0,600)
// (k<300: Wih col k; k>=300: Whh col k-300). Plus bias sums bsum[dir][1200].
// ------------------------------------------------------------------
__global__ void tr_lstm(const float* __restrict__ allf, float* __restrict__ wLT,
                        float* __restrict__ bsum) {
  int idx = blockIdx.x * 256 + threadIdx.x;
  if (idx < 1440000) {
    int dir = idx / 720000;
    int rem = idx - dir * 720000;
    int k = rem / 1200, gj = rem - (rem / 1200) * 1200;
    int src;
    if (k < 300) src = (dir ? AF_LWIH_B : AF_LWIH_F) + gj * 300 + k;
    else         src = (dir ? AF_LWHH_B : AF_LWHH_F) + gj * 300 + (k - 300);
    wLT[idx] = allf[src];
  } else if (idx < 1442400) {
    int i2 = idx - 1440000;
    int dir = i2 / 1200, gj = i2 - (i2 / 1200) * 1200;
    bsum[i2] = allf[(dir ? AF_LBIH_B : AF_LBIH_F) + gj]
             + allf[(dir ? AF_LBHH_B : AF_LBHH_F) + gj];
  }
}

// ------------------------------------------------------------------
// LSTM step v5: tiled GEMM + fused cell. Grid (8 rowt[64], 10 jt[32], 2 dir),
// 256 thr. Thread owns 4 rows x 2 j x 4 gates = 32 acc.
// K=600 in 75 slices of BK=8; Xs[8][68], Ws[8][136] in LDS (~6.8KB).
// ------------------------------------------------------------------
struct Lstm5Args {
  const int* sents; const int* lens;
  const void* emb;
  const float* wLT; const float* bsum;
  const int* flag;
  float* h;      // [parity][dir][512][300]
  float* c;      // [dir][512][300]
  float* maxb;   // [512][600]
  int s;
};

__global__ __launch_bounds__(256) void lstm5(Lstm5Args a) {
  __shared__ int   tokL[64];
  __shared__ float Xs[8][68];       // [kk][row]
  __shared__ float Ws[8 * 136];     // [kk][g*34 + jj]
  const int tid = threadIdx.x;
  const int r0  = blockIdx.x * 64;
  const int j0  = blockIdx.y * 32;
  const int dir = blockIdx.z;
  const int s   = a.s;
  const int tt  = dir ? (S_LEN - 1 - s) : s;
  const int rp  = s & 1;
  const float* hread  = a.h + (size_t)(rp * 2 + dir) * B_SZ * H_LS;
  float*       hwrite = a.h + (size_t)((1 - rp) * 2 + dir) * B_SZ * H_LS;
  const int fl = *a.flag;
  const float* wbase = a.wLT + (size_t)dir * 720000;

  if (tid < 64) tokL[tid] = a.sents[(r0 + tid) * S_LEN + tt];
  __syncthreads();

  const int tj = tid & 15;          // j-pair: j = j0 + tj*2
  const int rg = tid >> 4;          // 0..15 : rows rg*4 .. rg*4+3
  float acc[4][2][4];
  #pragma unroll
  for (int rr = 0; rr < 4; ++rr)
    #pragma unroll
    for (int jj = 0; jj < 2; ++jj)
      #pragma unroll
      for (int g = 0; g < 4; ++g) acc[rr][jj][g] = 0.f;

  for (int k0 = 0; k0 < 600; k0 += 8) {
    // stage X: 512 floats, 2/thread; lin -> r=lin/8, kk=lin&7 (coalesced in k)
    #pragma unroll
    for (int i = 0; i < 2; ++i) {
      int lin = i * 256 + tid;
      int r = lin >> 3, kk = lin & 7;
      int k = k0 + kk;
      float v;
      if (k < 300) {
        v = fl ? u2f(((const u16*)a.emb)[(size_t)tokL[r] * 300 + k])
               : ((const float*)a.emb)[(size_t)tokL[r] * 300 + k];
      } else {
        v = (s > 0) ? hread[(size_t)(r0 + r) * H_LS + (k - 300)] : 0.f;
      }
      Xs[kk][r] = v;
    }
    // stage W: 1024 floats, 4/thread; lin -> kk=lin/128, g=(lin%128)/32, jj=lin%32
    #pragma unroll
    for (int i = 0; i < 4; ++i) {
      int lin = i * 256 + tid;
      int kk = lin >> 7, rem = lin & 127;
      int g = rem >> 5, jj = rem & 31;
      float wv = 0.f;
      if (j0 + jj < 300)
        wv = wbase[(size_t)(k0 + kk) * 1200 + g * 300 + j0 + jj];
      Ws[kk * 136 + g * 34 + jj] = wv;
    }
    __syncthreads();
    #pragma unroll
    for (int kk = 0; kk < 8; ++kk) {
      float4 xv = *(const float4*)&Xs[kk][rg * 4];
      float xa[4] = {xv.x, xv.y, xv.z, xv.w};
      #pragma unroll
      for (int g = 0; g < 4; ++g) {
        float2 wv = *(const float2*)&Ws[kk * 136 + g * 34 + tj * 2];
        #pragma unroll
        for (int rr = 0; rr < 4; ++rr) {
          acc[rr][0][g] += xa[rr] * wv.x;
          acc[rr][1][g] += xa[rr] * wv.y;
        }
      }
    }
    __syncthreads();
  }

  // epilogue: cell update for 4 rows x 2 j
  const float* bs = a.bsum + dir * 1200;
  #pragma unroll
  for (int rr = 0; rr < 4; ++rr) {
    int b = r0 + rg * 4 + rr;
    bool m = tt < a.lens[b];
    #pragma unroll
    for (int jj = 0; jj < 2; ++jj) {
      int j = j0 + tj * 2 + jj;
      if (j >= 300) continue;
      float gi = acc[rr][jj][0] + bs[j];
      float gf = acc[rr][jj][1] + bs[300 + j];
      float gg = acc[rr][jj][2] + bs[600 + j];
      float go = acc[rr][jj][3] + bs[900 + j];
      size_t cix = ((size_t)dir * B_SZ + b) * H_LS + j;
      size_t hix = (size_t)b * H_LS + j;
      float outv = 0.f;
      if (m) {
        float cp = (s == 0) ? 0.f : a.c[cix];
        float cn = sigm(gf) * cp + sigm(gi) * tanhf(gg);
        float hn = sigm(go) * tanhf(cn);
        a.c[cix] = cn;
        hwrite[hix] = hn;
        outv = hn;
      } else {
        if (s == 0) { a.c[cix] = 0.f; hwrite[hix] = 0.f; }
        else hwrite[hix] = hread[hix];
      }
      size_t mix = (size_t)b * 600 + dir * 300 + j;
      a.maxb[mix] = (s == 0) ? outv : fmaxf(a.maxb[mix], outv);
    }
  }
}

// ------------------------------------------------------------------
// s_utt = tanh(maxpl @ lin1_W^T + lin1_b)   [512,100]
// ------------------------------------------------------------------
__global__ __launch_bounds__(128) void sutt_k(const float* __restrict__ maxb,
                                              const float* __restrict__ W,
                                              const float* __restrict__ bb,
                                              float* __restrict__ sutt) {
  int b = blockIdx.x, tid = threadIdx.x;
  __shared__ float mx[600];
  for (int i = tid; i < 600; i += 128) mx[i] = maxb[b * 600 + i];
  __syncthreads();
  if (tid < 100) {
    float acc = bb[tid];
    const float* wr = W + tid * 600;
    for (int k = 0; k < 600; ++k) acc += mx[k] * wr[k];
    sutt[b * 100 + tid] = tanhf(acc);
  }
}

// ------------------------------------------------------------------
// GRU x-projection: xg[dir][t][row][300] f32 (incl. bih)
// ------------------------------------------------------------------
__global__ __launch_bounds__(256) void gxg3(const float* __restrict__ sutt,
                                            const float* __restrict__ Wf, const float* __restrict__ bf_,
                                            const float* __restrict__ Wb, const float* __restrict__ bb_,
                                            float* __restrict__ xg) {
  __shared__ float bts[32][101];
  int tid = threadIdx.x;
  int rt = blockIdx.x * 32, t = blockIdx.y, dir = blockIdx.z;
  int tin = dir ? (39 - t) : t;
  for (int idx = tid; idx < 3200; idx += 256) {
    int r = idx / 100, k = idx - r * 100, row = rt + r;
    float v = 0.f;
    if (row < BM1) {
      int srow = row + 1 - 40 + tin;
      if (srow >= 0) v = sutt[srow * 100 + k];
    }
    bts[r][k] = v;
  }
  __syncthreads();
  const float* Wm = dir ? Wb : Wf;
  const float* bm = dir ? bb_ : bf_;
  for (int o = tid; o < 9600; o += 256) {
    int r = o & 31, g = o >> 5;
    float acc = bm[g];
    const float* wr = Wm + g * 100;
    const float* br = bts[r];
    for (int k = 0; k < 100; ++k) acc += br[k] * wr[k];
    int row = rt + r;
    if (row < BM1) xg[(((size_t)dir * 40 + t) * BM1 + row) * 300 + g] = acc;
  }
}

// ------------------------------------------------------------------
// GRU scan v4 (validated r9): 512 thr, register-h, ping-pong, prefetch.
// ------------------------------------------------------------------
struct Gru4Args {
  const float* wt;
  const float* bhh[2];
  const float* xg;
  float* memf; float* memb;
};

__global__ __launch_bounds__(512) void gru4(Gru4Args a) {
  __shared__ float WT[30000];
  __shared__ float hl[2][4][104];
  int tid = threadIdx.x, rt = blockIdx.x * 4, dir = blockIdx.y;
  const float* src = a.wt + dir * 30000;
  for (int i = tid; i < 30000; i += 512) WT[i] = src[i];
  for (int i = tid; i < 832; i += 512) ((float*)hl)[i] = 0.f;
  int r = tid / 100, j = tid - r * 100;
  int row = rt + r;
  bool act = (tid < 400) && (row < BM1);
  const float* bhh = a.bhh[dir];
  float xr = 0.f, xz = 0.f, xn = 0.f;
  if (act) {
    size_t xb = ((size_t)(dir * 40) * BM1 + row) * 300;
    xr = a.xg[xb + j]; xz = a.xg[xb + 100 + j]; xn = a.xg[xb + 200 + j];
  }
  float hprev = 0.f;
  __syncthreads();
  for (int t = 0; t < 40; ++t) {
    int nxt = (t + 1) & 1, cur = t & 1;
    float xr2 = 0.f, xz2 = 0.f, xn2 = 0.f;
    if (act && t < 39) {
      size_t xb = ((size_t)(dir * 40 + t + 1) * BM1 + row) * 300;
      xr2 = a.xg[xb + j]; xz2 = a.xg[xb + 100 + j]; xn2 = a.xg[xb + 200 + j];
    }
    float v = 0.f;
    if (act) {
      float hr = bhh[j], hz = bhh[100 + j], hn = bhh[200 + j];
      const float* w0 = WT + j;
      const float* hrow = hl[cur][r];
      for (int k = 0; k < 100; ++k) {
        float hv = hrow[k];
        hr += hv * w0[k * 100];
        hz += hv * w0[10000 + k * 100];
        hn += hv * w0[20000 + k * 100];
      }
      float rg_ = sigm(xr + hr), zg = sigm(xz + hz);
      float ng = tanhf(xn + rg_ * hn);
      v = (1.f - zg) * ng + zg * hprev;
      int tin = dir ? (39 - t) : t;
      (dir ? a.memb : a.memf)[((size_t)tin * BM1 + row) * 100 + j] = v;
    }
    if (tid < 400) hl[nxt][r][j] = v;
    hprev = v;
    __syncthreads();
    xr = xr2; xz = xz2; xn = xn2;
  }
}

// mem = bt + mem_f + mem_b
__global__ void memcomb(const float* __restrict__ memf, const float* __restrict__ memb,
                        const float* __restrict__ sutt, float* __restrict__ memm) {
  int idx = blockIdx.x * 256 + threadIdx.x;
  if (idx >= 40 * BM1 * 100) return;
  int j = idx % 100; int rem = idx / 100; int row = rem % BM1; int t = rem / BM1;
  float v = memf[idx] + memb[idx];
  int sidx = row + 1 - 40 + t;
  if (sidx >= 0) v += sutt[sidx * 100 + j];
  memm[idx] = v;
}

__global__ void epsinit(const float* __restrict__ sutt, float* __restrict__ eps) {
  int idx = blockIdx.x * 256 + threadIdx.x;
  if (idx < BM1 * 100) eps[idx] = sutt[idx + 100];
}

// attention scores + softmax -> gates + attn output (f32)
__global__ __launch_bounds__(64) void attnsc(const float* __restrict__ eps,
                                             const float* __restrict__ memm,
                                             float* __restrict__ gatesw,
                                             float* __restrict__ outat) {
  int row = blockIdx.x, k = threadIdx.x;
  __shared__ float el[100];
  for (int i = k; i < 100; i += 64) el[i] = eps[row * 100 + i];
  __syncthreads();
  float val = -INFINITY;
  if (k < 40) {
    if (row + 1 - 40 + k >= 0) {
      const float* mrow = memm + ((size_t)k * BM1 + row) * 100;
      float s = 0.f;
      for (int d = 0; d < 100; ++d) s += el[d] * mrow[d];
      val = s;
    } else val = -1e10f;
  }
  float mx = val;
  for (int off = 32; off > 0; off >>= 1) mx = fmaxf(mx, __shfl_xor(mx, off));
  float ex = (k < 40) ? expf(val - mx) : 0.f;
  float sm = ex;
  for (int off = 32; off > 0; off >>= 1) sm += __shfl_xor(sm, off);
  if (k < 40) {
    float sc = ex / sm;
    gatesw[k * BM1 + row] = sc;
    outat[row * 40 + k] = sc;
  }
}

// cr/cw precompute GEMM: grid (16, 40, 2)
__global__ __launch_bounds__(256) void crcw3(const float* __restrict__ memm,
                                             const float* __restrict__ Wr, const float* __restrict__ br,
                                             const float* __restrict__ Ww, const float* __restrict__ bw,
                                             float* __restrict__ crb, float* __restrict__ cwb) {
  __shared__ float ml[32][101];
  int tid = threadIdx.x;
  int rt = blockIdx.x * 32, t = blockIdx.y, which = blockIdx.z;
  for (int idx = tid; idx < 3200; idx += 256) {
    int r = idx / 100, k = idx - r * 100; int row = rt + r;
    ml[r][k] = (row < BM1) ? memm[((size_t)t * BM1 + row) * 100 + k] : 0.f;
  }
  __syncthreads();
  const float* Wm = which ? Ww : Wr;
  const float* bm = which ? bw : br;
  float* ob = which ? cwb : crb;
  for (int o = tid; o < 3200; o += 256) {
    int r = o & 31, hh = o >> 5;
    float acc = bm[hh];
    const float* wr = Wm + hh * 100;
    for (int k = 0; k < 100; ++k) acc += ml[r][k] * wr[k];
    int row = rt + r;
    if (row < BM1) ob[((size_t)t * BM1 + row) * 100 + hh] = acc;
  }
}

// ------------------------------------------------------------------
// AttnGRU scan v4 (validated r9): 512 thr, register-h, ping-pong, prefetch.
// ------------------------------------------------------------------
struct Att4Args {
  const float* urT; const float* uT;
  const float* bur; const float* bu;
  const float* crb; const float* cwb;
  const float* gatesw; float* eps;
};

__global__ __launch_bounds__(512) void attscan4(Att4Args a) {
  __shared__ float UrT[10000];
  __shared__ float UT[10000];
  __shared__ float hl[2][4][104];
  int tid = threadIdx.x, rt = blockIdx.x * 4;
  for (int i = tid; i < 10000; i += 512) { UrT[i] = a.urT[i]; UT[i] = a.uT[i]; }
  for (int i = tid; i < 832; i += 512) ((float*)hl)[i] = 0.f;
  int r = tid / 100, j = tid - r * 100;
  int row = rt + r;
  bool act = (tid < 400) && (row < BM1);
  float cr = 0.f, cw = 0.f, gw = 0.f;
  if (act) {
    size_t ix = (size_t)row * 100 + j;
    cr = a.crb[ix]; cw = a.cwb[ix]; gw = a.gatesw[row];
  }
  float hprev = 0.f;
  __syncthreads();
  for (int t = 0; t < 40; ++t) {
    int nxt = (t + 1) & 1, cur = t & 1;
    float cr2 = 0.f, cw2 = 0.f, gw2 = 0.f;
    if (act && t < 39) {
      size_t ix = ((size_t)(t + 1) * BM1 + row) * 100 + j;
      cr2 = a.crb[ix]; cw2 = a.cwb[ix]; gw2 = a.gatesw[(t + 1) * BM1 + row];
    }
    float v = 0.f;
    if (act) {
      float hr = a.bur[j], hu = a.bu[j];
      const float* hrow = hl[cur][r];
      for (int k = 0; k < 100; ++k) {
        float hv = hrow[k];
        hr += hv * UrT[k * 100 + j];
        hu += hv * UT[k * 100 + j];
      }
      float rg_ = sigm(cr + hr);
      float ht = tanhf(cw + rg_ * hu);
      v = gw * ht + (1.f - gw) * hprev;
    }
    if (tid < 400) hl[nxt][r][j] = v;
    hprev = v;
    __syncthreads();
    cr = cr2; cw = cw2; gw = gw2;
  }
  if (act) a.eps[(size_t)row * 100 + j] += hprev;
}

// classifier -> f32
__global__ __launch_bounds__(64) void cls_k(const float* __restrict__ sutt,
                                            const float* __restrict__ eps,
                                            const float* __restrict__ cW, const float* __restrict__ cb,
                                            float* __restrict__ outp) {
  int b = blockIdx.x, j = threadIdx.x;
  __shared__ float sl[100];
  for (int i = j; i < 100; i += 64) sl[i] = (b == 0) ? sutt[i] : eps[(b - 1) * 100 + i];
  __syncthreads();
  float lg = -INFINITY;
  if (j < 7) {
    lg = cb[j];
    const float* wr = cW + j * 100;
    for (int k = 0; k < 100; ++k) lg += sl[k] * wr[k];
  }
  float mx = lg;
  for (int off = 32; off > 0; off >>= 1) mx = fmaxf(mx, __shfl_xor(mx, off));
  float ex = (j < 7) ? expf(lg - mx) : 0.f;
  float sm = ex;
  for (int off = 32; off > 0; off >>= 1) sm += __shfl_xor(sm, off);
  if (j < 7) outp[b * 7 + j] = lg - mx - logf(sm);
}

// ------------------------------------------------------------------
extern "C" void kernel_launch(void* const* d_in, const int* in_sizes, int n_in,
                              void* d_out, int out_size, void* d_ws, size_t ws_size,
                              hipStream_t stream) {
  (void)n_in; (void)out_size; (void)ws_size;

  bool sigOrder = (in_sizes[7] == 360000);   // r4 evidence: dict order

  const void *p_sents, *p_lens, *p_emb;
  const void *p_lWih_f, *p_lWhh_f, *p_lbih_f, *p_lbhh_f;
  const void *p_lWih_b, *p_lWhh_b, *p_lbih_b, *p_lbhh_b;
  const void *p_gWih_f, *p_gWhh_f, *p_gbih_f, *p_gbhh_f;
  const void *p_gWih_b, *p_gWhh_b, *p_gbih_b, *p_gbhh_b;
  const void *p_lin1W, *p_lin1b;
  const void *p_attWr, *p_attUr, *p_attW, *p_attU;
  const void *p_attbr, *p_attbur, *p_attbw, *p_attbu;
  const void *p_clsW, *p_clsb;

  p_sents = d_in[0]; p_lens = d_in[1]; p_emb = d_in[2];
  p_lWih_f = d_in[3]; p_lWhh_f = d_in[4]; p_lbih_f = d_in[5]; p_lbhh_f = d_in[6];
  if (sigOrder) {
    p_lWih_b = d_in[7];  p_lWhh_b = d_in[8];  p_lbih_b = d_in[9];  p_lbhh_b = d_in[10];
    p_lin1W  = d_in[11]; p_lin1b  = d_in[12];
    p_gWih_f = d_in[13]; p_gWhh_f = d_in[14]; p_gbih_f = d_in[15]; p_gbhh_f = d_in[16];
    p_gWih_b = d_in[17]; p_gWhh_b = d_in[18]; p_gbih_b = d_in[19]; p_gbhh_b = d_in[20];
    p_attWr  = d_in[21]; p_attbr  = d_in[22]; p_attUr  = d_in[23]; p_attbur = d_in[24];
    p_attW   = d_in[25]; p_attbw  = d_in[26]; p_attU   = d_in[27]; p_attbu  = d_in[28];
    p_clsW   = d_in[29]; p_clsb   = d_in[30];
  } else {
    p_gWih_f = d_in[7];  p_gWhh_f = d_in[8];  p_gbih_f = d_in[9];  p_gbhh_f = d_in[10];
    p_lWih_b = d_in[11]; p_lWhh_b = d_in[12]; p_lbih_b = d_in[13]; p_lbhh_b = d_in[14];
    p_gWih_b = d_in[15]; p_gWhh_b = d_in[16]; p_gbih_b = d_in[17]; p_gbhh_b = d_in[18];
    p_lin1W  = d_in[19]; p_lin1b  = d_in[20];
    p_attWr  = d_in[21]; p_attUr  = d_in[22]; p_attW   = d_in[23]; p_attU   = d_in[24];
    p_attbr  = d_in[25]; p_attbur = d_in[26]; p_attbw  = d_in[27]; p_attbu  = d_in[28];
    p_clsW   = d_in[29]; p_clsb   = d_in[30];
  }

  char* wp = (char*)d_ws;
  auto carve = [&](size_t bytes) {
    char* p = wp;
    wp += (bytes + 255) & ~(size_t)255;
    return p;
  };
  int*   flag  = (int*)  carve(256);
  float* allf  = (float*)carve((size_t)NF_TOT * 4);
  float* wt    = (float*)carve((size_t)120000 * 4);
  float* wLT   = (float*)carve((size_t)1440000 * 4);
  float* bsum  = (float*)carve((size_t)2400 * 4);
  float* hbuf  = (float*)carve((size_t)2 * 2 * B_SZ * H_LS * 4);
  float* cst   = (float*)carve((size_t)2 * B_SZ * H_LS * 4);
  float* maxb  = (float*)carve((size_t)B_SZ * 600 * 4);
  float* sutt  = (float*)carve((size_t)B_SZ * 100 * 4);
  float* xg    = (float*)carve((size_t)2 * 40 * BM1 * 300 * 4);
  float* memf  = (float*)carve((size_t)40 * BM1 * 100 * 4);
  float* memb  = (float*)carve((size_t)40 * BM1 * 100 * 4);
  float* memm  = (float*)carve((size_t)40 * BM1 * 100 * 4);
  float* gatesw= (float*)carve((size_t)40 * BM1 * 4);
  float* eps   = (float*)carve((size_t)BM1 * 100 * 4);
  // crb/cwb alias into xg (xg dead after gru4; stream-ordered)
  float* crb   = xg;
  float* cwb   = xg + (size_t)40 * BM1 * 100;

  float* out_pred = (float*)d_out;
  float* out_attn = out_pred + (size_t)B_SZ * NC_;

  detect_k<<<1, 256, 0, stream>>>((const u32*)p_emb, flag);

  NormFArgs nf;
  {
    const void* srcs[NF_NSEG] = {
      p_lWih_f, p_lWhh_f, p_lWih_b, p_lWhh_b,
      p_lbih_f, p_lbhh_f, p_lbih_b, p_lbhh_b,
      p_gWih_f, p_gWhh_f, p_gbih_f, p_gbhh_f,
      p_gWih_b, p_gWhh_b, p_gbih_b, p_gbhh_b,
      p_lin1W,  p_lin1b,
      p_attWr,  p_attUr,  p_attW,   p_attU,
      p_attbr,  p_attbur, p_attbw,  p_attbu,
      p_clsW,   p_clsb };
    for (int i = 0; i < NF_NSEG; ++i) nf.src[i] = srcs[i];
    nf.flag = flag; nf.dst = allf;
  }
  norm_f32<<<2048, 256, 0, stream>>>(nf);
  transp_k<<<(120000 + 255) / 256, 256, 0, stream>>>(allf, wt);
  tr_lstm<<<(1442400 + 255) / 256, 256, 0, stream>>>(allf, wLT, bsum);

  Lstm5Args la;
  la.sents = (const int*)p_sents; la.lens = (const int*)p_lens;
  la.emb = p_emb;
  la.wLT = wLT; la.bsum = bsum;
  la.flag = flag;
  la.h = hbuf; la.c = cst; la.maxb = maxb;
  for (int s = 0; s < S_LEN; ++s) {
    la.s = s;
    lstm5<<<dim3(8, 10, 2), 256, 0, stream>>>(la);
  }

  sutt_k<<<512, 128, 0, stream>>>(maxb, allf + AF_LIN1W, allf + AF_LIN1B, sutt);

  gxg3<<<dim3(16, 40, 2), 256, 0, stream>>>(sutt,
      allf + AF_GWIH_F, allf + AF_GBIH_F,
      allf + AF_GWIH_B, allf + AF_GBIH_B, xg);

  Gru4Args ga;
  ga.wt = wt;
  ga.bhh[0] = allf + AF_GBHH_F; ga.bhh[1] = allf + AF_GBHH_B;
  ga.xg = xg; ga.memf = memf; ga.memb = memb;
  gru4<<<dim3(128, 2), 512, 0, stream>>>(ga);

  memcomb<<<(40 * BM1 * 100 + 255) / 256, 256, 0, stream>>>(memf, memb, sutt, memm);
  epsinit<<<(BM1 * 100 + 255) / 256, 256, 0, stream>>>(sutt, eps);

  for (int hop = 0; hop < NHOP; ++hop) {
    attnsc<<<BM1, 64, 0, stream>>>(eps, memm, gatesw, out_attn + (size_t)hop * BM1 * 40);
    crcw3<<<dim3(16, 40, 2), 256, 0, stream>>>(memm,
        allf + AF_ATTWR + hop * 10000, allf + AF_ATTBR + hop * 100,
        allf + AF_ATTW  + hop * 10000, allf + AF_ATTBW + hop * 100, crb, cwb);
    Att4Args aa;
    aa.urT = wt + 60000 + hop * 10000;
    aa.uT  = wt + 90000 + hop * 10000;
    aa.bur = allf + AF_ATTBUR + hop * 100;
    aa.bu  = allf + AF_ATTBU  + hop * 100;
    aa.crb = crb; aa.cwb = cwb;
    aa.gatesw = gatesw; aa.eps = eps;
    attscan4<<<128, 512, 0, stream>>>(aa);
  }

  cls_k<<<512, 64, 0, stream>>>(sutt, eps, allf + AF_CLSW, allf + AF_CLSB, out_pred);
}

// Round 11
// 15242.430 us; speedup vs baseline: 1.1053x; 1.0943x over previous
//
#include <hip/hip_runtime.h>
#include <cstdint>
#include <cstddef>

typedef unsigned short u16;
typedef unsigned int   u32;

#define S_LEN 100
#define B_SZ  512
#define H_LS  300
#define NHOP  3
#define NC_   7
#define BM1   511   // B-1
#define NBD   100   // lstm6 blocks per dir
#define LBK   30    // lstm6 K-slice

__device__ __forceinline__ float u2f(u16 u) {
  union { u32 i; float f; } x; x.i = ((u32)u) << 16; return x.f;
}
__device__ __forceinline__ float sigm(float x) { return 1.0f / (1.0f + expf(-x)); }

// ------------------------------------------------------------------
// dtype detect on emb raw bits (validated r1->r2)
// ------------------------------------------------------------------
__global__ void detect_k(const u32* __restrict__ raw, int* __restrict__ flag) {
  __shared__ int cnt;
  if (threadIdx.x == 0) cnt = 0;
  __syncthreads();
  u32 w = raw[threadIdx.x];
  u32 lo = w & 0xFFFFu;
  int e = (int)((lo >> 7) & 0xFF);
  int pl = (lo == 0u || (e >= 0x70 && e <= 0x8E)) ? 1 : 0;
  atomicAdd(&cnt, pl);
  __syncthreads();
  if (threadIdx.x == 0) *flag = (cnt >= 192) ? 1 : 0;   // 1 = bf16 device data
}

// ------------------------------------------------------------------
// normalize ALL float params -> f32 mirror allf (validated r6/r7)
// ------------------------------------------------------------------
#define NF_NSEG 28
#define NF_TOT  1748007
struct NormFArgs { const void* src[NF_NSEG]; const int* flag; float* dst; };

__global__ __launch_bounds__(256) void norm_f32(NormFArgs a) {
  const int P[NF_NSEG + 1] = {
    0,360000,720000,1080000,1440000,1441200,1442400,1443600,
    1444800,1474800,1504800,1505100,1505400,1535400,1565400,1565700,
    1566000,1626000,1626100,1656100,1686100,1716100,1746100,1746400,
    1746700,1747000,1747300,1748000,1748007};
  int fl = *a.flag;
  int stride = gridDim.x * 256;
  for (int i = blockIdx.x * 256 + threadIdx.x; i < NF_TOT; i += stride) {
    int s = 0;
    while (i >= P[s + 1]) ++s;
    int k = i - P[s];
    float v = fl ? u2f(((const u16*)a.src[s])[k]) : ((const float*)a.src[s])[k];
    a.dst[i] = v;
  }
}
#define AF_LWIH_F 0
#define AF_LWHH_F 360000
#define AF_LWIH_B 720000
#define AF_LWHH_B 1080000
#define AF_LBIH_F 1440000
#define AF_LBHH_F 1441200
#define AF_LBIH_B 1442400
#define AF_LBHH_B 1443600
#define AF_GWIH_F 1444800
#define AF_GWHH_F 1474800
#define AF_GBIH_F 1504800
#define AF_GBHH_F 1505100
#define AF_GWIH_B 1505400
#define AF_GWHH_B 1535400
#define AF_GBIH_B 1565400
#define AF_GBHH_B 1565700
#define AF_LIN1W  1566000
#define AF_LIN1B  1626000
#define AF_ATTWR  1626100
#define AF_ATTUR  1656100
#define AF_ATTW   1686100
#define AF_ATTU   1716100
#define AF_ATTBR  1746100
#define AF_ATTBUR 1746400
#define AF_ATTBW  1746700
#define AF_ATTBU  1747000
#define AF_CLSW   1747300
#define AF_CLSB   1748000

// ------------------------------------------------------------------
// transpose 100x100 chunks to k-major: gWhh (2x3) + att Ur/U (3 hops x2)
// ------------------------------------------------------------------
__global__ void transp_k(const float* __restrict__ allf, float* __restrict__ wt) {
  int idx = blockIdx.x * 256 + threadIdx.x;
  if (idx >= 120000) return;
  int seg = idx / 10000;
  int rem = idx - seg * 10000;
  int k = rem / 100, j = rem - (rem / 100) * 100;
  int srcbase;
  if (seg < 3)      srcbase = AF_GWHH_F + seg * 10000;
  else if (seg < 6) srcbase = AF_GWHH_B + (seg - 3) * 10000;
  else if (seg < 9) srcbase = AF_ATTUR + (seg - 6) * 10000;
  else              srcbase = AF_ATTU  + (seg - 9) * 10000;
  wt[seg * 10000 + k * 100 + j] = allf[srcbase + j * 100 + k];
}

// ------------------------------------------------------------------
// LSTM weights -> k-major: wLT[dir][k][g*300+j], k in [0,600)
// Plus bias sums bsum[dir][1200].
// ------------------------------------------------------------------
__global__ void tr_lstm(const float* __restrict__ allf, float* __restrict__ wLT,
                        float* __restrict__ bsum) {
  int idx = blockIdx.x * 256 + threadIdx.x;
  if (idx < 1440000) {
    int dir = idx / 720000;
    int rem = idx - dir * 720000;
    int k = rem / 1200, gj = rem - (rem / 1200) * 1200;
    int src;
    if (k < 300) src = (dir ? AF_LWIH_B : AF_LWIH_F) + gj * 300 + k;
    else         src = (dir ? AF_LWHH_B : AF_LWHH_F) + gj * 300 + (k - 300);
    wLT[idx] = allf[src];
  } else if (idx < 1442400) {
    int i2 = idx - 1440000;
    int dir = i2 / 1200, gj = i2 - (i2 / 1200) * 1200;
    bsum[i2] = allf[(dir ? AF_LBIH_B : AF_LBIH_F) + gj]
             + allf[(dir ? AF_LBHH_B : AF_LBHH_F) + gj];
  }
}

// ------------------------------------------------------------------
// gather + transpose emb: xallT[t][k][r] = emb[sents[r][t]][k]
// grid (8 rtiles of 64, 100 t), 256 thr
// ------------------------------------------------------------------
__global__ __launch_bounds__(256) void xgather(const int* __restrict__ sents,
                                               const void* __restrict__ emb,
                                               const int* __restrict__ flag,
                                               float* __restrict__ xallT) {
  __shared__ float tile[64][301];
  __shared__ int toks[64];
  int tid = threadIdx.x;
  int r0 = blockIdx.x * 64, t = blockIdx.y;
  int fl = *flag;
  if (tid < 64) toks[tid] = sents[(r0 + tid) * S_LEN + t];
  __syncthreads();
  for (int idx = tid; idx < 64 * 300; idx += 256) {
    int r = idx / 300, k = idx - r * 300;
    tile[r][k] = fl ? u2f(((const u16*)emb)[(size_t)toks[r] * 300 + k])
                    : ((const float*)emb)[(size_t)toks[r] * 300 + k];
  }
  __syncthreads();
  for (int idx = tid; idx < 300 * 64; idx += 256) {
    int k = idx / 64, r = idx - k * 64;
    xallT[((size_t)t * 300 + k) * 512 + r0 + r] = tile[r][k];
  }
}

// ------------------------------------------------------------------
// LSTM persistent scan v6: grid (NBD=100, 2 dir), 512 thr, 1 block/CU.
// Block owns 3 h-dims x all 512 rows; weights (28.8KB) in LDS once.
// Per step: stage X|h slices -> acc; cell in registers; write hbufT;
// per-dir grid barrier (device-scope atomics + threadfence).
// ------------------------------------------------------------------
struct Lstm6Args {
  const int* lens;
  const float* xallT;   // [100][300][512]
  const float* wLT;     // [dir][600][1200]
  const float* bsum;    // [dir][1200]
  float* hbufT;         // [2 parity][2 dir][300][512]
  float* maxb;          // [512][600]
  int* cnt;             // per-dir counters at cnt[0], cnt[16]
};

__global__ __launch_bounds__(512, 1) void lstm6(Lstm6Args a) {
  __shared__ float WL[600 * 12];     // 28.8 KB
  __shared__ float Xs[LBK][512];     // 61.4 KB
  const int tid = threadIdx.x;
  const int bq  = blockIdx.x;
  const int dir = blockIdx.y;
  const int j0  = bq * 3;
  const float* wbase = a.wLT + (size_t)dir * 720000;
  for (int i = tid; i < 7200; i += 512) {
    int k = i / 12, c = i - k * 12;
    WL[i] = wbase[(size_t)k * 1200 + (c / 3) * 300 + j0 + (c % 3)];
  }
  float bs[12];
  #pragma unroll
  for (int c = 0; c < 12; ++c)
    bs[c] = a.bsum[dir * 1200 + (c / 3) * 300 + j0 + (c % 3)];

  const int r = tid;
  const int len = a.lens[r];
  float hq[3] = {0.f, 0.f, 0.f};
  float cq[3] = {0.f, 0.f, 0.f};
  float mx[3] = {-INFINITY, -INFINITY, -INFINITY};
  int* cptr = a.cnt + dir * 16;
  int target = 0;
  __syncthreads();

  for (int s = 0; s < S_LEN; ++s) {
    const int tt  = dir ? (S_LEN - 1 - s) : s;
    const int cur = s & 1, nxt = cur ^ 1;
    float acc[12];
    #pragma unroll
    for (int c = 0; c < 12; ++c) acc[c] = 0.f;

    for (int k0 = 0; k0 < 600; k0 += LBK) {
      for (int idx = tid; idx < LBK * 512; idx += 512) {
        int kk = idx >> 9, rr = idx & 511;
        int k = k0 + kk;
        float v;
        if (k < 300) v = a.xallT[((size_t)tt * 300 + k) * 512 + rr];
        else v = a.hbufT[(((size_t)cur * 2 + dir) * 300 + (k - 300)) * 512 + rr];
        Xs[kk][rr] = v;
      }
      __syncthreads();
      #pragma unroll
      for (int kk = 0; kk < LBK; ++kk) {
        float xv = Xs[kk][r];
        const float* w = WL + (k0 + kk) * 12;
        #pragma unroll
        for (int c = 0; c < 12; ++c) acc[c] = fmaf(xv, w[c], acc[c]);
      }
      __syncthreads();
    }

    bool m = tt < len;
    #pragma unroll
    for (int jj = 0; jj < 3; ++jj) {
      if (m) {
        float gi = acc[jj]     + bs[jj];
        float gf = acc[3 + jj] + bs[3 + jj];
        float gg = acc[6 + jj] + bs[6 + jj];
        float go = acc[9 + jj] + bs[9 + jj];
        cq[jj] = sigm(gf) * cq[jj] + sigm(gi) * tanhf(gg);
        hq[jj] = sigm(go) * tanhf(cq[jj]);
        mx[jj] = fmaxf(mx[jj], hq[jj]);
      } else {
        mx[jj] = fmaxf(mx[jj], 0.f);
      }
      a.hbufT[(((size_t)nxt * 2 + dir) * 300 + (j0 + jj)) * 512 + r] = hq[jj];
    }

    // per-dir grid barrier
    target += NBD;
    __syncthreads();
    if (tid == 0) {
      __threadfence();
      __hip_atomic_fetch_add(cptr, 1, __ATOMIC_ACQ_REL, __HIP_MEMORY_SCOPE_AGENT);
      while (__hip_atomic_load(cptr, __ATOMIC_ACQUIRE, __HIP_MEMORY_SCOPE_AGENT) < target) {
        __builtin_amdgcn_s_sleep(1);
      }
      __threadfence();
    }
    __syncthreads();
  }

  #pragma unroll
  for (int jj = 0; jj < 3; ++jj)
    a.maxb[(size_t)r * 600 + dir * 300 + j0 + jj] = mx[jj];
}

// ------------------------------------------------------------------
// s_utt = tanh(maxpl @ lin1_W^T + lin1_b)   [512,100]
// ------------------------------------------------------------------
__global__ __launch_bounds__(128) void sutt_k(const float* __restrict__ maxb,
                                              const float* __restrict__ W,
                                              const float* __restrict__ bb,
                                              float* __restrict__ sutt) {
  int b = blockIdx.x, tid = threadIdx.x;
  __shared__ float mx[600];
  for (int i = tid; i < 600; i += 128) mx[i] = maxb[b * 600 + i];
  __syncthreads();
  if (tid < 100) {
    float acc = bb[tid];
    const float* wr = W + tid * 600;
    for (int k = 0; k < 600; ++k) acc += mx[k] * wr[k];
    sutt[b * 100 + tid] = tanhf(acc);
  }
}

// ------------------------------------------------------------------
// GRU x-projection: xg[dir][t][row][300] f32 (incl. bih)
// ------------------------------------------------------------------
__global__ __launch_bounds__(256) void gxg3(const float* __restrict__ sutt,
                                            const float* __restrict__ Wf, const float* __restrict__ bf_,
                                            const float* __restrict__ Wb, const float* __restrict__ bb_,
                                            float* __restrict__ xg) {
  __shared__ float bts[32][101];
  int tid = threadIdx.x;
  int rt = blockIdx.x * 32, t = blockIdx.y, dir = blockIdx.z;
  int tin = dir ? (39 - t) : t;
  for (int idx = tid; idx < 3200; idx += 256) {
    int r = idx / 100, k = idx - r * 100, row = rt + r;
    float v = 0.f;
    if (row < BM1) {
      int srow = row + 1 - 40 + tin;
      if (srow >= 0) v = sutt[srow * 100 + k];
    }
    bts[r][k] = v;
  }
  __syncthreads();
  const float* Wm = dir ? Wb : Wf;
  const float* bm = dir ? bb_ : bf_;
  for (int o = tid; o < 9600; o += 256) {
    int r = o & 31, g = o >> 5;
    float acc = bm[g];
    const float* wr = Wm + g * 100;
    const float* br = bts[r];
    for (int k = 0; k < 100; ++k) acc += br[k] * wr[k];
    int row = rt + r;
    if (row < BM1) xg[(((size_t)dir * 40 + t) * BM1 + row) * 300 + g] = acc;
  }
}

// ------------------------------------------------------------------
// GRU scan v4 (validated r9): 512 thr, register-h, ping-pong, prefetch.
// ------------------------------------------------------------------
struct Gru4Args {
  const float* wt;
  const float* bhh[2];
  const float* xg;
  float* memf; float* memb;
};

__global__ __launch_bounds__(512) void gru4(Gru4Args a) {
  __shared__ float WT[30000];
  __shared__ float hl[2][4][104];
  int tid = threadIdx.x, rt = blockIdx.x * 4, dir = blockIdx.y;
  const float* src = a.wt + dir * 30000;
  for (int i = tid; i < 30000; i += 512) WT[i] = src[i];
  for (int i = tid; i < 832; i += 512) ((float*)hl)[i] = 0.f;
  int r = tid / 100, j = tid - r * 100;
  int row = rt + r;
  bool act = (tid < 400) && (row < BM1);
  const float* bhh = a.bhh[dir];
  float xr = 0.f, xz = 0.f, xn = 0.f;
  if (act) {
    size_t xb = ((size_t)(dir * 40) * BM1 + row) * 300;
    xr = a.xg[xb + j]; xz = a.xg[xb + 100 + j]; xn = a.xg[xb + 200 + j];
  }
  float hprev = 0.f;
  __syncthreads();
  for (int t = 0; t < 40; ++t) {
    int nxt = (t + 1) & 1, cur = t & 1;
    float xr2 = 0.f, xz2 = 0.f, xn2 = 0.f;
    if (act && t < 39) {
      size_t xb = ((size_t)(dir * 40 + t + 1) * BM1 + row) * 300;
      xr2 = a.xg[xb + j]; xz2 = a.xg[xb + 100 + j]; xn2 = a.xg[xb + 200 + j];
    }
    float v = 0.f;
    if (act) {
      float hr = bhh[j], hz = bhh[100 + j], hn = bhh[200 + j];
      const float* w0 = WT + j;
      const float* hrow = hl[cur][r];
      for (int k = 0; k < 100; ++k) {
        float hv = hrow[k];
        hr += hv * w0[k * 100];
        hz += hv * w0[10000 + k * 100];
        hn += hv * w0[20000 + k * 100];
      }
      float rg_ = sigm(xr + hr), zg = sigm(xz + hz);
      float ng = tanhf(xn + rg_ * hn);
      v = (1.f - zg) * ng + zg * hprev;
      int tin = dir ? (39 - t) : t;
      (dir ? a.memb : a.memf)[((size_t)tin * BM1 + row) * 100 + j] = v;
    }
    if (tid < 400) hl[nxt][r][j] = v;
    hprev = v;
    __syncthreads();
    xr = xr2; xz = xz2; xn = xn2;
  }
}

// mem = bt + mem_f + mem_b
__global__ void memcomb(const float* __restrict__ memf, const float* __restrict__ memb,
                        const float* __restrict__ sutt, float* __restrict__ memm) {
  int idx = blockIdx.x * 256 + threadIdx.x;
  if (idx >= 40 * BM1 * 100) return;
  int j = idx % 100; int rem = idx / 100; int row = rem % BM1; int t = rem / BM1;
  float v = memf[idx] + memb[idx];
  int sidx = row + 1 - 40 + t;
  if (sidx >= 0) v += sutt[sidx * 100 + j];
  memm[idx] = v;
}

__global__ void epsinit(const float* __restrict__ sutt, float* __restrict__ eps) {
  int idx = blockIdx.x * 256 + threadIdx.x;
  if (idx < BM1 * 100) eps[idx] = sutt[idx + 100];
}

// attention scores + softmax -> gates + attn output (f32)
__global__ __launch_bounds__(64) void attnsc(const float* __restrict__ eps,
                                             const float* __restrict__ memm,
                                             float* __restrict__ gatesw,
                                             float* __restrict__ outat) {
  int row = blockIdx.x, k = threadIdx.x;
  __shared__ float el[100];
  for (int i = k; i < 100; i += 64) el[i] = eps[row * 100 + i];
  __syncthreads();
  float val = -INFINITY;
  if (k < 40) {
    if (row + 1 - 40 + k >= 0) {
      const float* mrow = memm + ((size_t)k * BM1 + row) * 100;
      float s = 0.f;
      for (int d = 0; d < 100; ++d) s += el[d] * mrow[d];
      val = s;
    } else val = -1e10f;
  }
  float mx = val;
  for (int off = 32; off > 0; off >>= 1) mx = fmaxf(mx, __shfl_xor(mx, off));
  float ex = (k < 40) ? expf(val - mx) : 0.f;
  float sm = ex;
  for (int off = 32; off > 0; off >>= 1) sm += __shfl_xor(sm, off);
  if (k < 40) {
    float sc = ex / sm;
    gatesw[k * BM1 + row] = sc;
    outat[row * 40 + k] = sc;
  }
}

// cr/cw precompute GEMM: grid (16, 40, 2)
__global__ __launch_bounds__(256) void crcw3(const float* __restrict__ memm,
                                             const float* __restrict__ Wr, const float* __restrict__ br,
                                             const float* __restrict__ Ww, const float* __restrict__ bw,
                                             float* __restrict__ crb, float* __restrict__ cwb) {
  __shared__ float ml[32][101];
  int tid = threadIdx.x;
  int rt = blockIdx.x * 32, t = blockIdx.y, which = blockIdx.z;
  for (int idx = tid; idx < 3200; idx += 256) {
    int r = idx / 100, k = idx - r * 100; int row = rt + r;
    ml[r][k] = (row < BM1) ? memm[((size_t)t * BM1 + row) * 100 + k] : 0.f;
  }
  __syncthreads();
  const float* Wm = which ? Ww : Wr;
  const float* bm = which ? bw : br;
  float* ob = which ? cwb : crb;
  for (int o = tid; o < 3200; o += 256) {
    int r = o & 31, hh = o >> 5;
    float acc = bm[hh];
    const float* wr = Wm + hh * 100;
    for (int k = 0; k < 100; ++k) acc += ml[r][k] * wr[k];
    int row = rt + r;
    if (row < BM1) ob[((size_t)t * BM1 + row) * 100 + hh] = acc;
  }
}

// ------------------------------------------------------------------
// AttnGRU scan v4 (validated r9)
// ------------------------------------------------------------------
struct Att4Args {
  const float* urT; const float* uT;
  const float* bur; const float* bu;
  const float* crb; const float* cwb;
  const float* gatesw; float* eps;
};

__global__ __launch_bounds__(512) void attscan4(Att4Args a) {
  __shared__ float UrT[10000];
  __shared__ float UT[10000];
  __shared__ float hl[2][4][104];
  int tid = threadIdx.x, rt = blockIdx.x * 4;
  for (int i = tid; i < 10000; i += 512) { UrT[i] = a.urT[i]; UT[i] = a.uT[i]; }
  for (int i = tid; i < 832; i += 512) ((float*)hl)[i] = 0.f;
  int r = tid / 100, j = tid - r * 100;
  int row = rt + r;
  bool act = (tid < 400) && (row < BM1);
  float cr = 0.f, cw = 0.f, gw = 0.f;
  if (act) {
    size_t ix = (size_t)row * 100 + j;
    cr = a.crb[ix]; cw = a.cwb[ix]; gw = a.gatesw[row];
  }
  float hprev = 0.f;
  __syncthreads();
  for (int t = 0; t < 40; ++t) {
    int nxt = (t + 1) & 1, cur = t & 1;
    float cr2 = 0.f, cw2 = 0.f, gw2 = 0.f;
    if (act && t < 39) {
      size_t ix = ((size_t)(t + 1) * BM1 + row) * 100 + j;
      cr2 = a.crb[ix]; cw2 = a.cwb[ix]; gw2 = a.gatesw[(t + 1) * BM1 + row];
    }
    float v = 0.f;
    if (act) {
      float hr = a.bur[j], hu = a.bu[j];
      const float* hrow = hl[cur][r];
      for (int k = 0; k < 100; ++k) {
        float hv = hrow[k];
        hr += hv * UrT[k * 100 + j];
        hu += hv * UT[k * 100 + j];
      }
      float rg_ = sigm(cr + hr);
      float ht = tanhf(cw + rg_ * hu);
      v = gw * ht + (1.f - gw) * hprev;
    }
    if (tid < 400) hl[nxt][r][j] = v;
    hprev = v;
    __syncthreads();
    cr = cr2; cw = cw2; gw = gw2;
  }
  if (act) a.eps[(size_t)row * 100 + j] += hprev;
}

// classifier -> f32
__global__ __launch_bounds__(64) void cls_k(const float* __restrict__ sutt,
                                            const float* __restrict__ eps,
                                            const float* __restrict__ cW, const float* __restrict__ cb,
                                            float* __restrict__ outp) {
  int b = blockIdx.x, j = threadIdx.x;
  __shared__ float sl[100];
  for (int i = j; i < 100; i += 64) sl[i] = (b == 0) ? sutt[i] : eps[(b - 1) * 100 + i];
  __syncthreads();
  float lg = -INFINITY;
  if (j < 7) {
    lg = cb[j];
    const float* wr = cW + j * 100;
    for (int k = 0; k < 100; ++k) lg += sl[k] * wr[k];
  }
  float mx = lg;
  for (int off = 32; off > 0; off >>= 1) mx = fmaxf(mx, __shfl_xor(mx, off));
  float ex = (j < 7) ? expf(lg - mx) : 0.f;
  float sm = ex;
  for (int off = 32; off > 0; off >>= 1) sm += __shfl_xor(sm, off);
  if (j < 7) outp[b * 7 + j] = lg - mx - logf(sm);
}

// ------------------------------------------------------------------
extern "C" void kernel_launch(void* const* d_in, const int* in_sizes, int n_in,
                              void* d_out, int out_size, void* d_ws, size_t ws_size,
                              hipStream_t stream) {
  (void)n_in; (void)out_size; (void)ws_size;

  bool sigOrder = (in_sizes[7] == 360000);   // r4 evidence: dict order

  const void *p_sents, *p_lens, *p_emb;
  const void *p_lWih_f, *p_lWhh_f, *p_lbih_f, *p_lbhh_f;
  const void *p_lWih_b, *p_lWhh_b, *p_lbih_b, *p_lbhh_b;
  const void *p_gWih_f, *p_gWhh_f, *p_gbih_f, *p_gbhh_f;
  const void *p_gWih_b, *p_gWhh_b, *p_gbih_b, *p_gbhh_b;
  const void *p_lin1W, *p_lin1b;
  const void *p_attWr, *p_attUr, *p_attW, *p_attU;
  const void *p_attbr, *p_attbur, *p_attbw, *p_attbu;
  const void *p_clsW, *p_clsb;

  p_sents = d_in[0]; p_lens = d_in[1]; p_emb = d_in[2];
  p_lWih_f = d_in[3]; p_lWhh_f = d_in[4]; p_lbih_f = d_in[5]; p_lbhh_f = d_in[6];
  if (sigOrder) {
    p_lWih_b = d_in[7];  p_lWhh_b = d_in[8];  p_lbih_b = d_in[9];  p_lbhh_b = d_in[10];
    p_lin1W  = d_in[11]; p_lin1b  = d_in[12];
    p_gWih_f = d_in[13]; p_gWhh_f = d_in[14]; p_gbih_f = d_in[15]; p_gbhh_f = d_in[16];
    p_gWih_b = d_in[17]; p_gWhh_b = d_in[18]; p_gbih_b = d_in[19]; p_gbhh_b = d_in[20];
    p_attWr  = d_in[21]; p_attbr  = d_in[22]; p_attUr  = d_in[23]; p_attbur = d_in[24];
    p_attW   = d_in[25]; p_attbw  = d_in[26]; p_attU   = d_in[27]; p_attbu  = d_in[28];
    p_clsW   = d_in[29]; p_clsb   = d_in[30];
  } else {
    p_gWih_f = d_in[7];  p_gWhh_f = d_in[8];  p_gbih_f = d_in[9];  p_gbhh_f = d_in[10];
    p_lWih_b = d_in[11]; p_lWhh_b = d_in[12]; p_lbih_b = d_in[13]; p_lbhh_b = d_in[14];
    p_gWih_b = d_in[15]; p_gWhh_b = d_in[16]; p_gbih_b = d_in[17]; p_gbhh_b = d_in[18];
    p_lin1W  = d_in[19]; p_lin1b  = d_in[20];
    p_attWr  = d_in[21]; p_attUr  = d_in[22]; p_attW   = d_in[23]; p_attU   = d_in[24];
    p_attbr  = d_in[25]; p_attbur = d_in[26]; p_attbw  = d_in[27]; p_attbu  = d_in[28];
    p_clsW   = d_in[29]; p_clsb   = d_in[30];
  }

  char* wp = (char*)d_ws;
  auto carve = [&](size_t bytes) {
    char* p = wp;
    wp += (bytes + 255) & ~(size_t)255;
    return p;
  };
  int*   flag  = (int*)  carve(256);
  int*   cnt   = (int*)  carve(256);
  float* allf  = (float*)carve((size_t)NF_TOT * 4);
  float* wt    = (float*)carve((size_t)120000 * 4);
  float* wLT   = (float*)carve((size_t)1440000 * 4);
  float* bsum  = (float*)carve((size_t)2400 * 4);
  float* hbufT = (float*)carve((size_t)2 * 2 * 300 * 512 * 4);
  float* maxb  = (float*)carve((size_t)B_SZ * 600 * 4);
  float* sutt  = (float*)carve((size_t)B_SZ * 100 * 4);
  // big region: xallT (61.44MB, dead after lstm6) aliases xg+memf+memb (65.4MB)
  size_t xg_sz   = (size_t)2 * 40 * BM1 * 300 * 4;
  size_t memf_sz = (size_t)40 * BM1 * 100 * 4;
  char*  big   = carve(xg_sz + 2 * memf_sz);
  float* xallT = (float*)big;
  float* xg    = (float*)big;
  float* memf  = (float*)(big + xg_sz);
  float* memb  = (float*)(big + xg_sz + memf_sz);
  float* memm  = (float*)carve(memf_sz);
  float* gatesw= (float*)carve((size_t)40 * BM1 * 4);
  float* eps   = (float*)carve((size_t)BM1 * 100 * 4);
  // crb/cwb alias into xg (xg dead after gru4; stream-ordered)
  float* crb   = xg;
  float* cwb   = xg + (size_t)40 * BM1 * 100;

  float* out_pred = (float*)d_out;
  float* out_attn = out_pred + (size_t)B_SZ * NC_;

  detect_k<<<1, 256, 0, stream>>>((const u32*)p_emb, flag);

  NormFArgs nf;
  {
    const void* srcs[NF_NSEG] = {
      p_lWih_f, p_lWhh_f, p_lWih_b, p_lWhh_b,
      p_lbih_f, p_lbhh_f, p_lbih_b, p_lbhh_b,
      p_gWih_f, p_gWhh_f, p_gbih_f, p_gbhh_f,
      p_gWih_b, p_gWhh_b, p_gbih_b, p_gbhh_b,
      p_lin1W,  p_lin1b,
      p_attWr,  p_attUr,  p_attW,   p_attU,
      p_attbr,  p_attbur, p_attbw,  p_attbu,
      p_clsW,   p_clsb };
    for (int i = 0; i < NF_NSEG; ++i) nf.src[i] = srcs[i];
    nf.flag = flag; nf.dst = allf;
  }
  norm_f32<<<2048, 256, 0, stream>>>(nf);
  transp_k<<<(120000 + 255) / 256, 256, 0, stream>>>(allf, wt);
  tr_lstm<<<(1442400 + 255) / 256, 256, 0, stream>>>(allf, wLT, bsum);
  xgather<<<dim3(8, 100), 256, 0, stream>>>((const int*)p_sents, p_emb, flag, xallT);

  hipMemsetAsync(cnt, 0, 256, stream);
  hipMemsetAsync(hbufT, 0, (size_t)2 * 2 * 300 * 512 * 4, stream);

  Lstm6Args la;
  la.lens = (const int*)p_lens;
  la.xallT = xallT; la.wLT = wLT; la.bsum = bsum;
  la.hbufT = hbufT; la.maxb = maxb; la.cnt = cnt;
  lstm6<<<dim3(NBD, 2), 512, 0, stream>>>(la);

  sutt_k<<<512, 128, 0, stream>>>(maxb, allf + AF_LIN1W, allf + AF_LIN1B, sutt);

  gxg3<<<dim3(16, 40, 2), 256, 0, stream>>>(sutt,
      allf + AF_GWIH_F, allf + AF_GBIH_F,
      allf + AF_GWIH_B, allf + AF_GBIH_B, xg);

  Gru4Args ga;
  ga.wt = wt;
  ga.bhh[0] = allf + AF_GBHH_F; ga.bhh[1] = allf + AF_GBHH_B;
  ga.xg = xg; ga.memf = memf; ga.memb = memb;
  gru4<<<dim3(128, 2), 512, 0, stream>>>(ga);

  memcomb<<<(40 * BM1 * 100 + 255) / 256, 256, 0, stream>>>(memf, memb, sutt, memm);
  epsinit<<<(BM1 * 100 + 255) / 256, 256, 0, stream>>>(sutt, eps);

  for (int hop = 0; hop < NHOP; ++hop) {
    attnsc<<<BM1, 64, 0, stream>>>(eps, memm, gatesw, out_attn + (size_t)hop * BM1 * 40);
    crcw3<<<dim3(16, 40, 2), 256, 0, stream>>>(memm,
        allf + AF_ATTWR + hop * 10000, allf + AF_ATTBR + hop * 100,
        allf + AF_ATTW  + hop * 10000, allf + AF_ATTBW + hop * 100, crb, cwb);
    Att4Args aa;
    aa.urT = wt + 60000 + hop * 10000;
    aa.uT  = wt + 90000 + hop * 10000;
    aa.bur = allf + AF_ATTBUR + hop * 100;
    aa.bu  = allf + AF_ATTBU  + hop * 100;
    aa.crb = crb; aa.cwb = cwb;
    aa.gatesw = gatesw; aa.eps = eps;
    attscan4<<<128, 512, 0, stream>>>(aa);
  }

  cls_k<<<512, 64, 0, stream>>>(sutt, eps, allf + AF_CLSW, allf + AF_CLSB, out_pred);
}

// Round 12
// 7709.314 us; speedup vs baseline: 2.1853x; 1.9771x over previous
//
#include <hip/hip_runtime.h>
#include <cstdint>
#include <cstddef>

typedef unsigned short u16;
typedef unsigned int   u32;

#define S_LEN 100
#define B_SZ  512
#define H_LS  300
#define NHOP  3
#define NC_   7
#define BM1   511   // B-1
#define NBD2  128   // lstm7 blocks per dir

__device__ __forceinline__ float u2f(u16 u) {
  union { u32 i; float f; } x; x.i = ((u32)u) << 16; return x.f;
}
__device__ __forceinline__ u16 f2u(float f) {
  u32 bits = __float_as_uint(f);
  bits += 0x7fffu + ((bits >> 16) & 1u);   // RNE
  return (u16)(bits >> 16);
}
__device__ __forceinline__ float sigm(float x) { return 1.0f / (1.0f + expf(-x)); }

// ------------------------------------------------------------------
// dtype detect on emb raw bits (validated r1->r2)
// ------------------------------------------------------------------
__global__ void detect_k(const u32* __restrict__ raw, int* __restrict__ flag) {
  __shared__ int cnt;
  if (threadIdx.x == 0) cnt = 0;
  __syncthreads();
  u32 w = raw[threadIdx.x];
  u32 lo = w & 0xFFFFu;
  int e = (int)((lo >> 7) & 0xFF);
  int pl = (lo == 0u || (e >= 0x70 && e <= 0x8E)) ? 1 : 0;
  atomicAdd(&cnt, pl);
  __syncthreads();
  if (threadIdx.x == 0) *flag = (cnt >= 192) ? 1 : 0;   // 1 = bf16 device data
}

// ------------------------------------------------------------------
// normalize ALL float params -> f32 mirror allf (validated r6/r7)
// ------------------------------------------------------------------
#define NF_NSEG 28
#define NF_TOT  1748007
struct NormFArgs { const void* src[NF_NSEG]; const int* flag; float* dst; };

__global__ __launch_bounds__(256) void norm_f32(NormFArgs a) {
  const int P[NF_NSEG + 1] = {
    0,360000,720000,1080000,1440000,1441200,1442400,1443600,
    1444800,1474800,1504800,1505100,1505400,1535400,1565400,1565700,
    1566000,1626000,1626100,1656100,1686100,1716100,1746100,1746400,
    1746700,1747000,1747300,1748000,1748007};
  int fl = *a.flag;
  int stride = gridDim.x * 256;
  for (int i = blockIdx.x * 256 + threadIdx.x; i < NF_TOT; i += stride) {
    int s = 0;
    while (i >= P[s + 1]) ++s;
    int k = i - P[s];
    float v = fl ? u2f(((const u16*)a.src[s])[k]) : ((const float*)a.src[s])[k];
    a.dst[i] = v;
  }
}
#define AF_LWIH_F 0
#define AF_LWHH_F 360000
#define AF_LWIH_B 720000
#define AF_LWHH_B 1080000
#define AF_LBIH_F 1440000
#define AF_LBHH_F 1441200
#define AF_LBIH_B 1442400
#define AF_LBHH_B 1443600
#define AF_GWIH_F 1444800
#define AF_GWHH_F 1474800
#define AF_GBIH_F 1504800
#define AF_GBHH_F 1505100
#define AF_GWIH_B 1505400
#define AF_GWHH_B 1535400
#define AF_GBIH_B 1565400
#define AF_GBHH_B 1565700
#define AF_LIN1W  1566000
#define AF_LIN1B  1626000
#define AF_ATTWR  1626100
#define AF_ATTUR  1656100
#define AF_ATTW   1686100
#define AF_ATTU   1716100
#define AF_ATTBR  1746100
#define AF_ATTBUR 1746400
#define AF_ATTBW  1746700
#define AF_ATTBU  1747000
#define AF_CLSW   1747300
#define AF_CLSB   1748000

// ------------------------------------------------------------------
// transpose 100x100 chunks to k-major: gWhh (2x3) + att Ur/U (3 hops x2)
// ------------------------------------------------------------------
__global__ void transp_k(const float* __restrict__ allf, float* __restrict__ wt) {
  int idx = blockIdx.x * 256 + threadIdx.x;
  if (idx >= 120000) return;
  int seg = idx / 10000;
  int rem = idx - seg * 10000;
  int k = rem / 100, j = rem - (rem / 100) * 100;
  int srcbase;
  if (seg < 3)      srcbase = AF_GWHH_F + seg * 10000;
  else if (seg < 6) srcbase = AF_GWHH_B + (seg - 3) * 10000;
  else if (seg < 9) srcbase = AF_ATTUR + (seg - 6) * 10000;
  else              srcbase = AF_ATTU  + (seg - 9) * 10000;
  wt[seg * 10000 + k * 100 + j] = allf[srcbase + j * 100 + k];
}

// ------------------------------------------------------------------
// LSTM weights -> k-major: wLT[dir][k][g*300+j], k in [0,600)
// Plus bias sums bsum[dir][1200].
// ------------------------------------------------------------------
__global__ void tr_lstm(const float* __restrict__ allf, float* __restrict__ wLT,
                        float* __restrict__ bsum) {
  int idx = blockIdx.x * 256 + threadIdx.x;
  if (idx < 1440000) {
    int dir = idx / 720000;
    int rem = idx - dir * 720000;
    int k = rem / 1200, gj = rem - (rem / 1200) * 1200;
    int src;
    if (k < 300) src = (dir ? AF_LWIH_B : AF_LWIH_F) + gj * 300 + k;
    else         src = (dir ? AF_LWHH_B : AF_LWHH_F) + gj * 300 + (k - 300);
    wLT[idx] = allf[src];
  } else if (idx < 1442400) {
    int i2 = idx - 1440000;
    int dir = i2 / 1200, gj = i2 - (i2 / 1200) * 1200;
    bsum[i2] = allf[(dir ? AF_LBIH_B : AF_LBIH_F) + gj]
             + allf[(dir ? AF_LBHH_B : AF_LBHH_F) + gj];
  }
}

// ------------------------------------------------------------------
// gather + transpose emb: xallT[t][k][r] = emb[sents[r][t]][k]
// ------------------------------------------------------------------
__global__ __launch_bounds__(256) void xgather(const int* __restrict__ sents,
                                               const void* __restrict__ emb,
                                               const int* __restrict__ flag,
                                               float* __restrict__ xallT) {
  __shared__ float tile[64][301];
  __shared__ int toks[64];
  int tid = threadIdx.x;
  int r0 = blockIdx.x * 64, t = blockIdx.y;
  int fl = *flag;
  if (tid < 64) toks[tid] = sents[(r0 + tid) * S_LEN + t];
  __syncthreads();
  for (int idx = tid; idx < 64 * 300; idx += 256) {
    int r = idx / 300, k = idx - r * 300;
    tile[r][k] = fl ? u2f(((const u16*)emb)[(size_t)toks[r] * 300 + k])
                    : ((const float*)emb)[(size_t)toks[r] * 300 + k];
  }
  __syncthreads();
  for (int idx = tid; idx < 300 * 64; idx += 256) {
    int k = idx / 64, r = idx - k * 64;
    xallT[((size_t)t * 300 + k) * 512 + r0 + r] = tile[r][k];
  }
}

// ------------------------------------------------------------------
// LSTM persistent scan v7: grid (8 rowT, 16 jT, 2 dir) = 256 blocks,
// 512 thr, 1 block/CU (141KB LDS). Block owns 64 rows x 20 j (80 gate
// cols); its 600x80 weight slice lives in LDS (bf16) for all 100 steps.
// Per step: K-sliced GEMM (BK=24, WLf f32 reconverted per slice),
// LDS gate exchange, cell update (c/max in LDS), per-dir grid barrier.
// ------------------------------------------------------------------
struct Lstm7Args {
  const int* lens;
  const float* xallT;   // [100][300][512]
  const float* wLT;     // [dir][600][1200]
  const float* bsum;    // [dir][1200]
  float* hbufT;         // [2 parity][2 dir][300][512]
  float* maxb;          // [512][600]
  int* cnt;             // per-dir counters at cnt[0], cnt[16]
};

__global__ __launch_bounds__(512, 1) void lstm7(Lstm7Args a) {
  __shared__ u16   WLh[600 * 80];    // 96000 B  (bf16 weight slice, persistent)
  __shared__ float WLf[24 * 80];     // 7680 B   (f32 slice of current BK)
  __shared__ float Xs[24 * 66];      // 6336 B
  __shared__ float Gs[64 * 80];      // 20480 B
  __shared__ float cs[20 * 64];      // 5120 B
  __shared__ float mxs[20 * 64];     // 5120 B
  __shared__ float bsL[80];
  __shared__ int   lensL[64];

  const int tid = threadIdx.x;
  const int r0  = blockIdx.x * 64;
  const int j0  = blockIdx.y * 20;
  const int dir = blockIdx.z;

  // ---- one-time init
  {
    const float* wbase = a.wLT + (size_t)dir * 720000;
    for (int i = tid; i < 48000; i += 512) {
      int k = i / 80, c = i - (i / 80) * 80;
      int g = c / 20, jj = c - g * 20;
      int j = j0 + jj;
      float wv = (j < 300) ? wbase[(size_t)k * 1200 + g * 300 + j] : 0.f;
      WLh[i] = f2u(wv);
    }
    if (tid < 80) {
      int g = tid / 20, jj = tid - g * 20, j = j0 + jj;
      bsL[tid] = (j < 300) ? a.bsum[dir * 1200 + g * 300 + j] : 0.f;
    }
    if (tid < 64) lensL[tid] = a.lens[r0 + tid];
    for (int i = tid; i < 1280; i += 512) { cs[i] = 0.f; mxs[i] = -INFINITY; }
  }
  int* cptr = a.cnt + dir * 16;
  int target = 0;
  const int rowg = tid >> 4;   // 0..31 (2 rows each)
  const int colg = tid & 15;   // 0..15 (5 cols each)
  __syncthreads();

  for (int s = 0; s < S_LEN; ++s) {
    const int tt  = dir ? (S_LEN - 1 - s) : s;
    const int cur = s & 1, nxt = cur ^ 1;
    float acc[10];
    #pragma unroll
    for (int i = 0; i < 10; ++i) acc[i] = 0.f;

    for (int k0 = 0; k0 < 600; k0 += 24) {
      // stage X|h tile slice: 24 k x 64 rows
      #pragma unroll
      for (int i = 0; i < 3; ++i) {
        int idx = i * 512 + tid;
        int kk = idx >> 6, rr = idx & 63;
        int k = k0 + kk;
        float v = (k < 300)
          ? a.xallT[((size_t)tt * 300 + k) * 512 + r0 + rr]
          : a.hbufT[(((size_t)cur * 2 + dir) * 300 + (k - 300)) * 512 + r0 + rr];
        Xs[kk * 66 + rr] = v;
      }
      // convert weight slice bf16 -> f32
      #pragma unroll
      for (int i = 0; i < 4; ++i) {
        int idx = i * 512 + tid;
        if (idx < 1920) WLf[idx] = u2f(WLh[k0 * 80 + idx]);
      }
      __syncthreads();
      #pragma unroll
      for (int kk = 0; kk < 24; ++kk) {
        float x0 = Xs[kk * 66 + rowg * 2];
        float x1 = Xs[kk * 66 + rowg * 2 + 1];
        const float* wrow = WLf + kk * 80 + colg * 5;
        #pragma unroll
        for (int cc = 0; cc < 5; ++cc) {
          float w = wrow[cc];
          acc[cc]     = fmaf(x0, w, acc[cc]);
          acc[5 + cc] = fmaf(x1, w, acc[5 + cc]);
        }
      }
      __syncthreads();
    }

    // gate exchange
    #pragma unroll
    for (int cc = 0; cc < 5; ++cc) {
      int c = colg * 5 + cc;
      Gs[(rowg * 2) * 80 + c]     = acc[cc];
      Gs[(rowg * 2 + 1) * 80 + c] = acc[5 + cc];
    }
    __syncthreads();

    // cell update: 1280 cells (64 r x 20 jj), r fastest for coalescing
    for (int idx = tid; idx < 1280; idx += 512) {
      int r = idx & 63, jj = idx >> 6;
      int j = j0 + jj;
      if (j < 300) {
        bool m = tt < lensL[r];
        float hv;
        if (m) {
          float gi = Gs[r * 80 + jj]      + bsL[jj];
          float gf = Gs[r * 80 + 20 + jj] + bsL[20 + jj];
          float gg = Gs[r * 80 + 40 + jj] + bsL[40 + jj];
          float go = Gs[r * 80 + 60 + jj] + bsL[60 + jj];
          float cp = cs[jj * 64 + r];
          float cn = sigm(gf) * cp + sigm(gi) * tanhf(gg);
          float hn = sigm(go) * tanhf(cn);
          cs[jj * 64 + r] = cn;
          hv = hn;
          mxs[jj * 64 + r] = fmaxf(mxs[jj * 64 + r], hn);
        } else {
          hv = a.hbufT[(((size_t)cur * 2 + dir) * 300 + j) * 512 + r0 + r];
          mxs[jj * 64 + r] = fmaxf(mxs[jj * 64 + r], 0.f);
        }
        a.hbufT[(((size_t)nxt * 2 + dir) * 300 + j) * 512 + r0 + r] = hv;
      }
    }

    // per-dir grid barrier (r11-validated pattern)
    target += NBD2;
    __syncthreads();
    if (tid == 0) {
      __threadfence();
      __hip_atomic_fetch_add(cptr, 1, __ATOMIC_ACQ_REL, __HIP_MEMORY_SCOPE_AGENT);
      while (__hip_atomic_load(cptr, __ATOMIC_ACQUIRE, __HIP_MEMORY_SCOPE_AGENT) < target) {
        __builtin_amdgcn_s_sleep(1);
      }
      __threadfence();
    }
    __syncthreads();
  }

  // write maxpool result
  for (int idx = tid; idx < 1280; idx += 512) {
    int r = idx & 63, jj = idx >> 6;
    int j = j0 + jj;
    if (j < 300)
      a.maxb[(size_t)(r0 + r) * 600 + dir * 300 + j] = mxs[jj * 64 + r];
  }
}

// ------------------------------------------------------------------
// s_utt = tanh(maxpl @ lin1_W^T + lin1_b)   [512,100]
// ------------------------------------------------------------------
__global__ __launch_bounds__(128) void sutt_k(const float* __restrict__ maxb,
                                              const float* __restrict__ W,
                                              const float* __restrict__ bb,
                                              float* __restrict__ sutt) {
  int b = blockIdx.x, tid = threadIdx.x;
  __shared__ float mx[600];
  for (int i = tid; i < 600; i += 128) mx[i] = maxb[b * 600 + i];
  __syncthreads();
  if (tid < 100) {
    float acc = bb[tid];
    const float* wr = W + tid * 600;
    for (int k = 0; k < 600; ++k) acc += mx[k] * wr[k];
    sutt[b * 100 + tid] = tanhf(acc);
  }
}

// ------------------------------------------------------------------
// GRU x-projection: xg[dir][t][row][300] f32 (incl. bih)
// ------------------------------------------------------------------
__global__ __launch_bounds__(256) void gxg3(const float* __restrict__ sutt,
                                            const float* __restrict__ Wf, const float* __restrict__ bf_,
                                            const float* __restrict__ Wb, const float* __restrict__ bb_,
                                            float* __restrict__ xg) {
  __shared__ float bts[32][101];
  int tid = threadIdx.x;
  int rt = blockIdx.x * 32, t = blockIdx.y, dir = blockIdx.z;
  int tin = dir ? (39 - t) : t;
  for (int idx = tid; idx < 3200; idx += 256) {
    int r = idx / 100, k = idx - r * 100, row = rt + r;
    float v = 0.f;
    if (row < BM1) {
      int srow = row + 1 - 40 + tin;
      if (srow >= 0) v = sutt[srow * 100 + k];
    }
    bts[r][k] = v;
  }
  __syncthreads();
  const float* Wm = dir ? Wb : Wf;
  const float* bm = dir ? bb_ : bf_;
  for (int o = tid; o < 9600; o += 256) {
    int r = o & 31, g = o >> 5;
    float acc = bm[g];
    const float* wr = Wm + g * 100;
    const float* br = bts[r];
    for (int k = 0; k < 100; ++k) acc += br[k] * wr[k];
    int row = rt + r;
    if (row < BM1) xg[(((size_t)dir * 40 + t) * BM1 + row) * 300 + g] = acc;
  }
}

// ------------------------------------------------------------------
// GRU scan v4 (validated r9)
// ------------------------------------------------------------------
struct Gru4Args {
  const float* wt;
  const float* bhh[2];
  const float* xg;
  float* memf; float* memb;
};

__global__ __launch_bounds__(512) void gru4(Gru4Args a) {
  __shared__ float WT[30000];
  __shared__ float hl[2][4][104];
  int tid = threadIdx.x, rt = blockIdx.x * 4, dir = blockIdx.y;
  const float* src = a.wt + dir * 30000;
  for (int i = tid; i < 30000; i += 512) WT[i] = src[i];
  for (int i = tid; i < 832; i += 512) ((float*)hl)[i] = 0.f;
  int r = tid / 100, j = tid - r * 100;
  int row = rt + r;
  bool act = (tid < 400) && (row < BM1);
  const float* bhh = a.bhh[dir];
  float xr = 0.f, xz = 0.f, xn = 0.f;
  if (act) {
    size_t xb = ((size_t)(dir * 40) * BM1 + row) * 300;
    xr = a.xg[xb + j]; xz = a.xg[xb + 100 + j]; xn = a.xg[xb + 200 + j];
  }
  float hprev = 0.f;
  __syncthreads();
  for (int t = 0; t < 40; ++t) {
    int nxt = (t + 1) & 1, cur = t & 1;
    float xr2 = 0.f, xz2 = 0.f, xn2 = 0.f;
    if (act && t < 39) {
      size_t xb = ((size_t)(dir * 40 + t + 1) * BM1 + row) * 300;
      xr2 = a.xg[xb + j]; xz2 = a.xg[xb + 100 + j]; xn2 = a.xg[xb + 200 + j];
    }
    float v = 0.f;
    if (act) {
      float hr = bhh[j], hz = bhh[100 + j], hn = bhh[200 + j];
      const float* w0 = WT + j;
      const float* hrow = hl[cur][r];
      for (int k = 0; k < 100; ++k) {
        float hv = hrow[k];
        hr += hv * w0[k * 100];
        hz += hv * w0[10000 + k * 100];
        hn += hv * w0[20000 + k * 100];
      }
      float rg_ = sigm(xr + hr), zg = sigm(xz + hz);
      float ng = tanhf(xn + rg_ * hn);
      v = (1.f - zg) * ng + zg * hprev;
      int tin = dir ? (39 - t) : t;
      (dir ? a.memb : a.memf)[((size_t)tin * BM1 + row) * 100 + j] = v;
    }
    if (tid < 400) hl[nxt][r][j] = v;
    hprev = v;
    __syncthreads();
    xr = xr2; xz = xz2; xn = xn2;
  }
}

// mem = bt + mem_f + mem_b
__global__ void memcomb(const float* __restrict__ memf, const float* __restrict__ memb,
                        const float* __restrict__ sutt, float* __restrict__ memm) {
  int idx = blockIdx.x * 256 + threadIdx.x;
  if (idx >= 40 * BM1 * 100) return;
  int j = idx % 100; int rem = idx / 100; int row = rem % BM1; int t = rem / BM1;
  float v = memf[idx] + memb[idx];
  int sidx = row + 1 - 40 + t;
  if (sidx >= 0) v += sutt[sidx * 100 + j];
  memm[idx] = v;
}

__global__ void epsinit(const float* __restrict__ sutt, float* __restrict__ eps) {
  int idx = blockIdx.x * 256 + threadIdx.x;
  if (idx < BM1 * 100) eps[idx] = sutt[idx + 100];
}

// attention scores + softmax -> gates + attn output (f32)
__global__ __launch_bounds__(64) void attnsc(const float* __restrict__ eps,
                                             const float* __restrict__ memm,
                                             float* __restrict__ gatesw,
                                             float* __restrict__ outat) {
  int row = blockIdx.x, k = threadIdx.x;
  __shared__ float el[100];
  for (int i = k; i < 100; i += 64) el[i] = eps[row * 100 + i];
  __syncthreads();
  float val = -INFINITY;
  if (k < 40) {
    if (row + 1 - 40 + k >= 0) {
      const float* mrow = memm + ((size_t)k * BM1 + row) * 100;
      float s = 0.f;
      for (int d = 0; d < 100; ++d) s += el[d] * mrow[d];
      val = s;
    } else val = -1e10f;
  }
  float mx = val;
  for (int off = 32; off > 0; off >>= 1) mx = fmaxf(mx, __shfl_xor(mx, off));
  float ex = (k < 40) ? expf(val - mx) : 0.f;
  float sm = ex;
  for (int off = 32; off > 0; off >>= 1) sm += __shfl_xor(sm, off);
  if (k < 40) {
    float sc = ex / sm;
    gatesw[k * BM1 + row] = sc;
    outat[row * 40 + k] = sc;
  }
}

// cr/cw precompute GEMM: grid (16, 40, 2)
__global__ __launch_bounds__(256) void crcw3(const float* __restrict__ memm,
                                             const float* __restrict__ Wr, const float* __restrict__ br,
                                             const float* __restrict__ Ww, const float* __restrict__ bw,
                                             float* __restrict__ crb, float* __restrict__ cwb) {
  __shared__ float ml[32][101];
  int tid = threadIdx.x;
  int rt = blockIdx.x * 32, t = blockIdx.y, which = blockIdx.z;
  for (int idx = tid; idx < 3200; idx += 256) {
    int r = idx / 100, k = idx - r * 100; int row = rt + r;
    ml[r][k] = (row < BM1) ? memm[((size_t)t * BM1 + row) * 100 + k] : 0.f;
  }
  __syncthreads();
  const float* Wm = which ? Ww : Wr;
  const float* bm = which ? bw : br;
  float* ob = which ? cwb : crb;
  for (int o = tid; o < 3200; o += 256) {
    int r = o & 31, hh = o >> 5;
    float acc = bm[hh];
    const float* wr = Wm + hh * 100;
    for (int k = 0; k < 100; ++k) acc += ml[r][k] * wr[k];
    int row = rt + r;
    if (row < BM1) ob[((size_t)t * BM1 + row) * 100 + hh] = acc;
  }
}

// ------------------------------------------------------------------
// AttnGRU scan v4 (validated r9)
// ------------------------------------------------------------------
struct Att4Args {
  const float* urT; const float* uT;
  const float* bur; const float* bu;
  const float* crb; const float* cwb;
  const float* gatesw; float* eps;
};

__global__ __launch_bounds__(512) void attscan4(Att4Args a) {
  __shared__ float UrT[10000];
  __shared__ float UT[10000];
  __shared__ float hl[2][4][104];
  int tid = threadIdx.x, rt = blockIdx.x * 4;
  for (int i = tid; i < 10000; i += 512) { UrT[i] = a.urT[i]; UT[i] = a.uT[i]; }
  for (int i = tid; i < 832; i += 512) ((float*)hl)[i] = 0.f;
  int r = tid / 100, j = tid - r * 100;
  int row = rt + r;
  bool act = (tid < 400) && (row < BM1);
  float cr = 0.f, cw = 0.f, gw = 0.f;
  if (act) {
    size_t ix = (size_t)row * 100 + j;
    cr = a.crb[ix]; cw = a.cwb[ix]; gw = a.gatesw[row];
  }
  float hprev = 0.f;
  __syncthreads();
  for (int t = 0; t < 40; ++t) {
    int nxt = (t + 1) & 1, cur = t & 1;
    float cr2 = 0.f, cw2 = 0.f, gw2 = 0.f;
    if (act && t < 39) {
      size_t ix = ((size_t)(t + 1) * BM1 + row) * 100 + j;
      cr2 = a.crb[ix]; cw2 = a.cwb[ix]; gw2 = a.gatesw[(t + 1) * BM1 + row];
    }
    float v = 0.f;
    if (act) {
      float hr = a.bur[j], hu = a.bu[j];
      const float* hrow = hl[cur][r];
      for (int k = 0; k < 100; ++k) {
        float hv = hrow[k];
        hr += hv * UrT[k * 100 + j];
        hu += hv * UT[k * 100 + j];
      }
      float rg_ = sigm(cr + hr);
      float ht = tanhf(cw + rg_ * hu);
      v = gw * ht + (1.f - gw) * hprev;
    }
    if (tid < 400) hl[nxt][r][j] = v;
    hprev = v;
    __syncthreads();
    cr = cr2; cw = cw2; gw = gw2;
  }
  if (act) a.eps[(size_t)row * 100 + j] += hprev;
}

// classifier -> f32
__global__ __launch_bounds__(64) void cls_k(const float* __restrict__ sutt,
                                            const float* __restrict__ eps,
                                            const float* __restrict__ cW, const float* __restrict__ cb,
                                            float* __restrict__ outp) {
  int b = blockIdx.x, j = threadIdx.x;
  __shared__ float sl[100];
  for (int i = j; i < 100; i += 64) sl[i] = (b == 0) ? sutt[i] : eps[(b - 1) * 100 + i];
  __syncthreads();
  float lg = -INFINITY;
  if (j < 7) {
    lg = cb[j];
    const float* wr = cW + j * 100;
    for (int k = 0; k < 100; ++k) lg += sl[k] * wr[k];
  }
  float mx = lg;
  for (int off = 32; off > 0; off >>= 1) mx = fmaxf(mx, __shfl_xor(mx, off));
  float ex = (j < 7) ? expf(lg - mx) : 0.f;
  float sm = ex;
  for (int off = 32; off > 0; off >>= 1) sm += __shfl_xor(sm, off);
  if (j < 7) outp[b * 7 + j] = lg - mx - logf(sm);
}

// ------------------------------------------------------------------
extern "C" void kernel_launch(void* const* d_in, const int* in_sizes, int n_in,
                              void* d_out, int out_size, void* d_ws, size_t ws_size,
                              hipStream_t stream) {
  (void)n_in; (void)out_size; (void)ws_size;

  bool sigOrder = (in_sizes[7] == 360000);   // r4 evidence: dict order

  const void *p_sents, *p_lens, *p_emb;
  const void *p_lWih_f, *p_lWhh_f, *p_lbih_f, *p_lbhh_f;
  const void *p_lWih_b, *p_lWhh_b, *p_lbih_b, *p_lbhh_b;
  const void *p_gWih_f, *p_gWhh_f, *p_gbih_f, *p_gbhh_f;
  const void *p_gWih_b, *p_gWhh_b, *p_gbih_b, *p_gbhh_b;
  const void *p_lin1W, *p_lin1b;
  const void *p_attWr, *p_attUr, *p_attW, *p_attU;
  const void *p_attbr, *p_attbur, *p_attbw, *p_attbu;
  const void *p_clsW, *p_clsb;

  p_sents = d_in[0]; p_lens = d_in[1]; p_emb = d_in[2];
  p_lWih_f = d_in[3]; p_lWhh_f = d_in[4]; p_lbih_f = d_in[5]; p_lbhh_f = d_in[6];
  if (sigOrder) {
    p_lWih_b = d_in[7];  p_lWhh_b = d_in[8];  p_lbih_b = d_in[9];  p_lbhh_b = d_in[10];
    p_lin1W  = d_in[11]; p_lin1b  = d_in[12];
    p_gWih_f = d_in[13]; p_gWhh_f = d_in[14]; p_gbih_f = d_in[15]; p_gbhh_f = d_in[16];
    p_gWih_b = d_in[17]; p_gWhh_b = d_in[18]; p_gbih_b = d_in[19]; p_gbhh_b = d_in[20];
    p_attWr  = d_in[21]; p_attbr  = d_in[22]; p_attUr  = d_in[23]; p_attbur = d_in[24];
    p_attW   = d_in[25]; p_attbw  = d_in[26]; p_attU   = d_in[27]; p_attbu  = d_in[28];
    p_clsW   = d_in[29]; p_clsb   = d_in[30];
  } else {
    p_gWih_f = d_in[7];  p_gWhh_f = d_in[8];  p_gbih_f = d_in[9];  p_gbhh_f = d_in[10];
    p_lWih_b = d_in[11]; p_lWhh_b = d_in[12]; p_lbih_b = d_in[13]; p_lbhh_b = d_in[14];
    p_gWih_b = d_in[15]; p_gWhh_b = d_in[16]; p_gbih_b = d_in[17]; p_gbhh_b = d_in[18];
    p_lin1W  = d_in[19]; p_lin1b  = d_in[20];
    p_attWr  = d_in[21]; p_attUr  = d_in[22]; p_attW   = d_in[23]; p_attU   = d_in[24];
    p_attbr  = d_in[25]; p_attbur = d_in[26]; p_attbw  = d_in[27]; p_attbu  = d_in[28];
    p_clsW   = d_in[29]; p_clsb   = d_in[30];
  }

  char* wp = (char*)d_ws;
  auto carve = [&](size_t bytes) {
    char* p = wp;
    wp += (bytes + 255) & ~(size_t)255;
    return p;
  };
  int*   flag  = (int*)  carve(256);
  int*   cnt   = (int*)  carve(256);
  float* allf  = (float*)carve((size_t)NF_TOT * 4);
  float* wt    = (float*)carve((size_t)120000 * 4);
  float* wLT   = (float*)carve((size_t)1440000 * 4);
  float* bsum  = (float*)carve((size_t)2400 * 4);
  float* hbufT = (float*)carve((size_t)2 * 2 * 300 * 512 * 4);
  float* maxb  = (float*)carve((size_t)B_SZ * 600 * 4);
  float* sutt  = (float*)carve((size_t)B_SZ * 100 * 4);
  // big region: xallT (61.44MB, dead after lstm7) aliases xg+memf+memb
  size_t xg_sz   = (size_t)2 * 40 * BM1 * 300 * 4;
  size_t memf_sz = (size_t)40 * BM1 * 100 * 4;
  char*  big   = carve(xg_sz + 2 * memf_sz);
  float* xallT = (float*)big;
  float* xg    = (float*)big;
  float* memf  = (float*)(big + xg_sz);
  float* memb  = (float*)(big + xg_sz + memf_sz);
  float* memm  = (float*)carve(memf_sz);
  float* gatesw= (float*)carve((size_t)40 * BM1 * 4);
  float* eps   = (float*)carve((size_t)BM1 * 100 * 4);
  float* crb   = xg;
  float* cwb   = xg + (size_t)40 * BM1 * 100;

  float* out_pred = (float*)d_out;
  float* out_attn = out_pred + (size_t)B_SZ * NC_;

  detect_k<<<1, 256, 0, stream>>>((const u32*)p_emb, flag);

  NormFArgs nf;
  {
    const void* srcs[NF_NSEG] = {
      p_lWih_f, p_lWhh_f, p_lWih_b, p_lWhh_b,
      p_lbih_f, p_lbhh_f, p_lbih_b, p_lbhh_b,
      p_gWih_f, p_gWhh_f, p_gbih_f, p_gbhh_f,
      p_gWih_b, p_gWhh_b, p_gbih_b, p_gbhh_b,
      p_lin1W,  p_lin1b,
      p_attWr,  p_attUr,  p_attW,   p_attU,
      p_attbr,  p_attbur, p_attbw,  p_attbu,
      p_clsW,   p_clsb };
    for (int i = 0; i < NF_NSEG; ++i) nf.src[i] = srcs[i];
    nf.flag = flag; nf.dst = allf;
  }
  norm_f32<<<2048, 256, 0, stream>>>(nf);
  transp_k<<<(120000 + 255) / 256, 256, 0, stream>>>(allf, wt);
  tr_lstm<<<(1442400 + 255) / 256, 256, 0, stream>>>(allf, wLT, bsum);
  xgather<<<dim3(8, 100), 256, 0, stream>>>((const int*)p_sents, p_emb, flag, xallT);

  hipMemsetAsync(cnt, 0, 256, stream);
  hipMemsetAsync(hbufT, 0, (size_t)2 * 2 * 300 * 512 * 4, stream);

  Lstm7Args la;
  la.lens = (const int*)p_lens;
  la.xallT = xallT; la.wLT = wLT; la.bsum = bsum;
  la.hbufT = hbufT; la.maxb = maxb; la.cnt = cnt;
  lstm7<<<dim3(8, 16, 2), 512, 0, stream>>>(la);

  sutt_k<<<512, 128, 0, stream>>>(maxb, allf + AF_LIN1W, allf + AF_LIN1B, sutt);

  gxg3<<<dim3(16, 40, 2), 256, 0, stream>>>(sutt,
      allf + AF_GWIH_F, allf + AF_GBIH_F,
      allf + AF_GWIH_B, allf + AF_GBIH_B, xg);

  Gru4Args ga;
  ga.wt = wt;
  ga.bhh[0] = allf + AF_GBHH_F; ga.bhh[1] = allf + AF_GBHH_B;
  ga.xg = xg; ga.memf = memf; ga.memb = memb;
  gru4<<<dim3(128, 2), 512, 0, stream>>>(ga);

  memcomb<<<(40 * BM1 * 100 + 255) / 256, 256, 0, stream>>>(memf, memb, sutt, memm);
  epsinit<<<(BM1 * 100 + 255) / 256, 256, 0, stream>>>(sutt, eps);

  for (int hop = 0; hop < NHOP; ++hop) {
    attnsc<<<BM1, 64, 0, stream>>>(eps, memm, gatesw, out_attn + (size_t)hop * BM1 * 40);
    crcw3<<<dim3(16, 40, 2), 256, 0, stream>>>(memm,
        allf + AF_ATTWR + hop * 10000, allf + AF_ATTBR + hop * 100,
        allf + AF_ATTW  + hop * 10000, allf + AF_ATTBW + hop * 100, crb, cwb);
    Att4Args aa;
    aa.urT = wt + 60000 + hop * 10000;
    aa.uT  = wt + 90000 + hop * 10000;
    aa.bur = allf + AF_ATTBUR + hop * 100;
    aa.bu  = allf + AF_ATTBU  + hop * 100;
    aa.crb = crb; aa.cwb = cwb;
    aa.gatesw = gatesw; aa.eps = eps;
    attscan4<<<128, 512, 0, stream>>>(aa);
  }

  cls_k<<<512, 64, 0, stream>>>(sutt, eps, allf + AF_CLSW, allf + AF_CLSB, out_pred);
}

// Round 13
// 3217.803 us; speedup vs baseline: 5.2357x; 2.3958x over previous
//
#include <hip/hip_runtime.h>
#include <cstdint>
#include <cstddef>

typedef unsigned short u16;
typedef unsigned int   u32;
typedef unsigned long long u64;

#define S_LEN 100
#define B_SZ  512
#define H_LS  300
#define NHOP  3
#define NC_   7
#define BM1   511   // B-1
#define NBD3  60    // lstm8 blocks per dir (4 row-tiles x 15 col-tiles)

using bf16x8 = __attribute__((ext_vector_type(8))) short;
using f32x4  = __attribute__((ext_vector_type(4))) float;

__device__ __forceinline__ float u2f(u16 u) {
  union { u32 i; float f; } x; x.i = ((u32)u) << 16; return x.f;
}
__device__ __forceinline__ u16 f2u(float f) {
  u32 bits = __float_as_uint(f);
  bits += 0x7fffu + ((bits >> 16) & 1u);   // RNE
  return (u16)(bits >> 16);
}
__device__ __forceinline__ float sigm(float x) { return 1.0f / (1.0f + expf(-x)); }

// ------------------------------------------------------------------
// dtype detect on emb raw bits (validated r1->r2)
// ------------------------------------------------------------------
__global__ void detect_k(const u32* __restrict__ raw, int* __restrict__ flag) {
  __shared__ int cnt;
  if (threadIdx.x == 0) cnt = 0;
  __syncthreads();
  u32 w = raw[threadIdx.x];
  u32 lo = w & 0xFFFFu;
  int e = (int)((lo >> 7) & 0xFF);
  int pl = (lo == 0u || (e >= 0x70 && e <= 0x8E)) ? 1 : 0;
  atomicAdd(&cnt, pl);
  __syncthreads();
  if (threadIdx.x == 0) *flag = (cnt >= 192) ? 1 : 0;   // 1 = bf16 device data
}

// ------------------------------------------------------------------
// normalize ALL float params -> f32 mirror allf (validated r6/r7)
// ------------------------------------------------------------------
#define NF_NSEG 28
#define NF_TOT  1748007
struct NormFArgs { const void* src[NF_NSEG]; const int* flag; float* dst; };

__global__ __launch_bounds__(256) void norm_f32(NormFArgs a) {
  const int P[NF_NSEG + 1] = {
    0,360000,720000,1080000,1440000,1441200,1442400,1443600,
    1444800,1474800,1504800,1505100,1505400,1535400,1565400,1565700,
    1566000,1626000,1626100,1656100,1686100,1716100,1746100,1746400,
    1746700,1747000,1747300,1748000,1748007};
  int fl = *a.flag;
  int stride = gridDim.x * 256;
  for (int i = blockIdx.x * 256 + threadIdx.x; i < NF_TOT; i += stride) {
    int s = 0;
    while (i >= P[s + 1]) ++s;
    int k = i - P[s];
    float v = fl ? u2f(((const u16*)a.src[s])[k]) : ((const float*)a.src[s])[k];
    a.dst[i] = v;
  }
}
#define AF_LWIH_F 0
#define AF_LWHH_F 360000
#define AF_LWIH_B 720000
#define AF_LWHH_B 1080000
#define AF_LBIH_F 1440000
#define AF_LBHH_F 1441200
#define AF_LBIH_B 1442400
#define AF_LBHH_B 1443600
#define AF_GWIH_F 1444800
#define AF_GWHH_F 1474800
#define AF_GBIH_F 1504800
#define AF_GBHH_F 1505100
#define AF_GWIH_B 1505400
#define AF_GWHH_B 1535400
#define AF_GBIH_B 1565400
#define AF_GBHH_B 1565700
#define AF_LIN1W  1566000
#define AF_LIN1B  1626000
#define AF_ATTWR  1626100
#define AF_ATTUR  1656100
#define AF_ATTW   1686100
#define AF_ATTU   1716100
#define AF_ATTBR  1746100
#define AF_ATTBUR 1746400
#define AF_ATTBW  1746700
#define AF_ATTBU  1747000
#define AF_CLSW   1747300
#define AF_CLSB   1748000

// ------------------------------------------------------------------
// transpose 100x100 chunks to k-major: gWhh (2x3) + att Ur/U (3 hops x2)
// ------------------------------------------------------------------
__global__ void transp_k(const float* __restrict__ allf, float* __restrict__ wt) {
  int idx = blockIdx.x * 256 + threadIdx.x;
  if (idx >= 120000) return;
  int seg = idx / 10000;
  int rem = idx - seg * 10000;
  int k = rem / 100, j = rem - (rem / 100) * 100;
  int srcbase;
  if (seg < 3)      srcbase = AF_GWHH_F + seg * 10000;
  else if (seg < 6) srcbase = AF_GWHH_B + (seg - 3) * 10000;
  else if (seg < 9) srcbase = AF_ATTUR + (seg - 6) * 10000;
  else              srcbase = AF_ATTU  + (seg - 9) * 10000;
  wt[seg * 10000 + k * 100 + j] = allf[srcbase + j * 100 + k];
}

// ------------------------------------------------------------------
// LSTM weights -> wL2[dir][c=j*4+g][k'=0..639] bf16 (K padded 2x320)
// k'<320: Wih col k' (0 if >=300); k'>=320: Whh col k'-320 (0 if >=300).
// Plus bias sums bsum[dir][g*300+j].
// ------------------------------------------------------------------
__global__ void tr_lstm2(const float* __restrict__ allf, u16* __restrict__ wL2,
                         float* __restrict__ bsum) {
  int idx = blockIdx.x * 256 + threadIdx.x;
  if (idx < 1536000) {
    int dir = idx / 768000;
    int rem = idx - dir * 768000;
    int c = rem / 640, kp = rem - (rem / 640) * 640;
    int j = c >> 2, g = c & 3;
    float v = 0.f;
    if (kp < 320) {
      if (kp < 300)
        v = allf[(dir ? AF_LWIH_B : AF_LWIH_F) + (g * 300 + j) * 300 + kp];
    } else {
      int k2 = kp - 320;
      if (k2 < 300)
        v = allf[(dir ? AF_LWHH_B : AF_LWHH_F) + (g * 300 + j) * 300 + k2];
    }
    wL2[idx] = f2u(v);
  } else if (idx < 1538400) {
    int i2 = idx - 1536000;
    int dir = i2 / 1200, gj = i2 - (i2 / 1200) * 1200;
    bsum[i2] = allf[(dir ? AF_LBIH_B : AF_LBIH_F) + gj]
             + allf[(dir ? AF_LBHH_B : AF_LBHH_F) + gj];
  }
}

// ------------------------------------------------------------------
// gather emb row-major bf16: xallR[t][r][320] (pad 300..319 = 0)
// ------------------------------------------------------------------
__global__ __launch_bounds__(256) void xgat2(const int* __restrict__ sents,
                                             const void* __restrict__ emb,
                                             const int* __restrict__ flag,
                                             u16* __restrict__ xallR) {
  __shared__ int toks[64];
  int tid = threadIdx.x;
  int r0 = blockIdx.x * 64, t = blockIdx.y;
  int fl = *flag;
  if (tid < 64) toks[tid] = sents[(r0 + tid) * S_LEN + t];
  __syncthreads();
  for (int idx = tid; idx < 64 * 320; idx += 256) {
    int r = idx / 320, k = idx - (idx / 320) * 320;
    u16 v = 0;
    if (k < 300) {
      size_t si = (size_t)toks[r] * 300 + k;
      v = fl ? ((const u16*)emb)[si] : f2u(((const float*)emb)[si]);
    }
    xallR[((size_t)t * 512 + r0 + r) * 320 + k] = v;
  }
}

// ------------------------------------------------------------------
// LSTM persistent MFMA scan v8: grid (4 rowT[128], 15 colT[80], 2 dir)
// = 120 blocks, 512 thr (8 waves), 1 block/CU (145KB LDS).
// Cols interleaved c = j*4+g (all gates of a j within one tile).
// W slice (80x640 bf16, XOR-swizzled rows) resident in LDS all 100 steps.
// A-frags direct from global: x bf16 (xallR), h f32->bf16 in-flight.
// MFMA fragment convention == r2/r3 bit-identical-validated scheme.
// Per step: 20 k-steps x {1 A-load, 5 B b128, 5 MFMA} per wave ->
// Gs exchange -> cell update (c/h/max in regs) -> per-dir grid barrier.
// ------------------------------------------------------------------
struct Lstm8Args {
  const int* lens;
  const u16* xallR;     // [100][512][320] bf16
  const u16* wL2;       // [dir][1200][640] bf16
  const float* bsum;    // [dir][1200] (g*300+j)
  float* hbufR;         // [2 par][2 dir][512][320] f32 (pad j>=300 stays 0)
  float* maxb;          // [512][600]
  int* cnt;             // per-dir counters at cnt[0], cnt[16]
};

__global__ __launch_bounds__(512, 1) void lstm8(Lstm8Args a) {
  __shared__ u16   WLh[80 * 640];    // 102400 B, swizzled: byte^=((cc&7)<<4)
  __shared__ float Gs[128][84];      // 43008 B
  const int tid = threadIdx.x;
  const int r0  = blockIdx.x * 128;
  const int ct  = blockIdx.y;        // 0..14 -> j0 = ct*20, c0 = ct*80
  const int dir = blockIdx.z;

  // ---- stage W slice once (80 cols x 640 u16 = 160 u64/row)
  {
    const u64* wsrc = (const u64*)(a.wL2 + (size_t)dir * 768000 + (size_t)ct * 80 * 640);
    for (int i = tid; i < 80 * 160; i += 512) {
      int cc = i / 160, kw = i - (i / 160) * 160;
      u64 v = wsrc[(size_t)cc * 160 + kw];
      *(u64*)((char*)WLh + cc * 1280 + ((kw * 8) ^ ((cc & 7) << 4))) = v;
    }
  }

  const int w  = tid >> 6;           // wave 0..7 -> row-frag w (16 rows)
  const int l  = tid & 63;
  const int lr = l & 15;
  const int aq = l >> 4;             // k-subgroup 0..3
  const int arow = r0 + w * 16 + lr;

  // ---- per-thread cells: 5 of (128 rows x 20 j)
  float cq[5], hq[5], mxv[5], bsv[5][4];
  int lenv[5];
  #pragma unroll
  for (int i = 0; i < 5; ++i) {
    int idx = tid * 5 + i;
    int r = idx / 20, jj = idx - (idx / 20) * 20;
    int j = ct * 20 + jj;
    cq[i] = 0.f; hq[i] = 0.f; mxv[i] = -INFINITY;
    lenv[i] = a.lens[r0 + r];
    #pragma unroll
    for (int g = 0; g < 4; ++g) bsv[i][g] = a.bsum[dir * 1200 + g * 300 + j];
  }

  int* cptr = a.cnt + dir * 16;
  int target = 0;
  __syncthreads();

  for (int s = 0; s < S_LEN; ++s) {
    const int tt  = dir ? (S_LEN - 1 - s) : s;
    const int cur = s & 1, nxt = cur ^ 1;

    f32x4 acc0 = {0,0,0,0}, acc1 = {0,0,0,0}, acc2 = {0,0,0,0},
          acc3 = {0,0,0,0}, acc4 = {0,0,0,0};

    const u16*   xrow = a.xallR + ((size_t)tt * 512 + arow) * 320 + aq * 8;
    const float* hrow = a.hbufR + (((size_t)cur * 2 + dir) * 512 + arow) * 320 + aq * 8;

    // x segment: ks 0..9 (A = bf16 direct)
    for (int ks = 0; ks < 10; ++ks) {
      bf16x8 Af = *(const bf16x8*)(xrow + ks * 32);
      #pragma unroll
      for (int cf = 0; cf < 5; ++cf) {
        int cc = cf * 16 + lr;
        bf16x8 Bf = *(const bf16x8*)((const char*)WLh + cc * 1280 +
                                     ((ks * 64 + aq * 16) ^ ((cc & 7) << 4)));
        f32x4& ac = (cf == 0) ? acc0 : (cf == 1) ? acc1 : (cf == 2) ? acc2
                  : (cf == 3) ? acc3 : acc4;
        ac = __builtin_amdgcn_mfma_f32_16x16x32_bf16(Af, Bf, ac, 0, 0, 0);
      }
    }
    // h segment: ks 10..19 (A = f32 -> bf16 pack)
    for (int ks = 0; ks < 10; ++ks) {
      const float* hp = hrow + ks * 32;
      float4 h0 = *(const float4*)hp;
      float4 h1 = *(const float4*)(hp + 4);
      union { u32 u[4]; bf16x8 v; } pk;
      pk.u[0] = ((u32)f2u(h0.y) << 16) | (u32)f2u(h0.x);
      pk.u[1] = ((u32)f2u(h0.w) << 16) | (u32)f2u(h0.z);
      pk.u[2] = ((u32)f2u(h1.y) << 16) | (u32)f2u(h1.x);
      pk.u[3] = ((u32)f2u(h1.w) << 16) | (u32)f2u(h1.z);
      bf16x8 Af = pk.v;
      #pragma unroll
      for (int cf = 0; cf < 5; ++cf) {
        int cc = cf * 16 + lr;
        bf16x8 Bf = *(const bf16x8*)((const char*)WLh + cc * 1280 +
                                     (((ks + 10) * 64 + aq * 16) ^ ((cc & 7) << 4)));
        f32x4& ac = (cf == 0) ? acc0 : (cf == 1) ? acc1 : (cf == 2) ? acc2
                  : (cf == 3) ? acc3 : acc4;
        ac = __builtin_amdgcn_mfma_f32_16x16x32_bf16(Af, Bf, ac, 0, 0, 0);
      }
    }

    // ---- gate exchange (C layout: row=(l>>4)*4+reg, col=l&15; r2-validated)
    #pragma unroll
    for (int rr = 0; rr < 4; ++rr) {
      Gs[w * 16 + aq * 4 + rr][0 * 16 + lr] = acc0[rr];
      Gs[w * 16 + aq * 4 + rr][1 * 16 + lr] = acc1[rr];
      Gs[w * 16 + aq * 4 + rr][2 * 16 + lr] = acc2[rr];
      Gs[w * 16 + aq * 4 + rr][3 * 16 + lr] = acc3[rr];
      Gs[w * 16 + aq * 4 + rr][4 * 16 + lr] = acc4[rr];
    }
    __syncthreads();

    // ---- cell update (gate order i,f,g,o at cols jj*4+g)
    #pragma unroll
    for (int i = 0; i < 5; ++i) {
      int idx = tid * 5 + i;
      int r = idx / 20, jj = idx - (idx / 20) * 20;
      bool m = tt < lenv[i];
      float4 g4 = *(const float4*)&Gs[r][jj * 4];
      if (m) {
        float gi = g4.x + bsv[i][0];
        float gf = g4.y + bsv[i][1];
        float gg = g4.z + bsv[i][2];
        float go = g4.w + bsv[i][3];
        cq[i] = sigm(gf) * cq[i] + sigm(gi) * tanhf(gg);
        hq[i] = sigm(go) * tanhf(cq[i]);
        mxv[i] = fmaxf(mxv[i], hq[i]);
      } else {
        mxv[i] = fmaxf(mxv[i], 0.f);
      }
      a.hbufR[(((size_t)nxt * 2 + dir) * 512 + r0 + r) * 320 + ct * 20 + jj] = hq[i];
    }

    // ---- per-dir grid barrier (r11/r12-validated pattern)
    target += NBD3;
    __syncthreads();
    if (tid == 0) {
      __threadfence();
      __hip_atomic_fetch_add(cptr, 1, __ATOMIC_ACQ_REL, __HIP_MEMORY_SCOPE_AGENT);
      while (__hip_atomic_load(cptr, __ATOMIC_ACQUIRE, __HIP_MEMORY_SCOPE_AGENT) < target) {
        __builtin_amdgcn_s_sleep(1);
      }
      __threadfence();
    }
    __syncthreads();
  }

  // ---- maxpool writeout
  #pragma unroll
  for (int i = 0; i < 5; ++i) {
    int idx = tid * 5 + i;
    int r = idx / 20, jj = idx - (idx / 20) * 20;
    a.maxb[(size_t)(r0 + r) * 600 + dir * 300 + ct * 20 + jj] = mxv[i];
  }
}

// ------------------------------------------------------------------
// s_utt = tanh(maxpl @ lin1_W^T + lin1_b)   [512,100]
// ------------------------------------------------------------------
__global__ __launch_bounds__(128) void sutt_k(const float* __restrict__ maxb,
                                              const float* __restrict__ W,
                                              const float* __restrict__ bb,
                                              float* __restrict__ sutt) {
  int b = blockIdx.x, tid = threadIdx.x;
  __shared__ float mx[600];
  for (int i = tid; i < 600; i += 128) mx[i] = maxb[b * 600 + i];
  __syncthreads();
  if (tid < 100) {
    float acc = bb[tid];
    const float* wr = W + tid * 600;
    for (int k = 0; k < 600; ++k) acc += mx[k] * wr[k];
    sutt[b * 100 + tid] = tanhf(acc);
  }
}

// ------------------------------------------------------------------
// GRU x-projection: xg[dir][t][row][300] f32 (incl. bih)
// ------------------------------------------------------------------
__global__ __launch_bounds__(256) void gxg3(const float* __restrict__ sutt,
                                            const float* __restrict__ Wf, const float* __restrict__ bf_,
                                            const float* __restrict__ Wb, const float* __restrict__ bb_,
                                            float* __restrict__ xg) {
  __shared__ float bts[32][101];
  int tid = threadIdx.x;
  int rt = blockIdx.x * 32, t = blockIdx.y, dir = blockIdx.z;
  int tin = dir ? (39 - t) : t;
  for (int idx = tid; idx < 3200; idx += 256) {
    int r = idx / 100, k = idx - r * 100, row = rt + r;
    float v = 0.f;
    if (row < BM1) {
      int srow = row + 1 - 40 + tin;
      if (srow >= 0) v = sutt[srow * 100 + k];
    }
    bts[r][k] = v;
  }
  __syncthreads();
  const float* Wm = dir ? Wb : Wf;
  const float* bm = dir ? bb_ : bf_;
  for (int o = tid; o < 9600; o += 256) {
    int r = o & 31, g = o >> 5;
    float acc = bm[g];
    const float* wr = Wm + g * 100;
    const float* br = bts[r];
    for (int k = 0; k < 100; ++k) acc += br[k] * wr[k];
    int row = rt + r;
    if (row < BM1) xg[(((size_t)dir * 40 + t) * BM1 + row) * 300 + g] = acc;
  }
}

// ------------------------------------------------------------------
// GRU scan v4 (validated r9)
// ------------------------------------------------------------------
struct Gru4Args {
  const float* wt;
  const float* bhh[2];
  const float* xg;
  float* memf; float* memb;
};

__global__ __launch_bounds__(512) void gru4(Gru4Args a) {
  __shared__ float WT[30000];
  __shared__ float hl[2][4][104];
  int tid = threadIdx.x, rt = blockIdx.x * 4, dir = blockIdx.y;
  const float* src = a.wt + dir * 30000;
  for (int i = tid; i < 30000; i += 512) WT[i] = src[i];
  for (int i = tid; i < 832; i += 512) ((float*)hl)[i] = 0.f;
  int r = tid / 100, j = tid - r * 100;
  int row = rt + r;
  bool act = (tid < 400) && (row < BM1);
  const float* bhh = a.bhh[dir];
  float xr = 0.f, xz = 0.f, xn = 0.f;
  if (act) {
    size_t xb = ((size_t)(dir * 40) * BM1 + row) * 300;
    xr = a.xg[xb + j]; xz = a.xg[xb + 100 + j]; xn = a.xg[xb + 200 + j];
  }
  float hprev = 0.f;
  __syncthreads();
  for (int t = 0; t < 40; ++t) {
    int nxt = (t + 1) & 1, cur = t & 1;
    float xr2 = 0.f, xz2 = 0.f, xn2 = 0.f;
    if (act && t < 39) {
      size_t xb = ((size_t)(dir * 40 + t + 1) * BM1 + row) * 300;
      xr2 = a.xg[xb + j]; xz2 = a.xg[xb + 100 + j]; xn2 = a.xg[xb + 200 + j];
    }
    float v = 0.f;
    if (act) {
      float hr = bhh[j], hz = bhh[100 + j], hn = bhh[200 + j];
      const float* w0 = WT + j;
      const float* hrow = hl[cur][r];
      for (int k = 0; k < 100; ++k) {
        float hv = hrow[k];
        hr += hv * w0[k * 100];
        hz += hv * w0[10000 + k * 100];
        hn += hv * w0[20000 + k * 100];
      }
      float rg_ = sigm(xr + hr), zg = sigm(xz + hz);
      float ng = tanhf(xn + rg_ * hn);
      v = (1.f - zg) * ng + zg * hprev;
      int tin = dir ? (39 - t) : t;
      (dir ? a.memb : a.memf)[((size_t)tin * BM1 + row) * 100 + j] = v;
    }
    if (tid < 400) hl[nxt][r][j] = v;
    hprev = v;
    __syncthreads();
    xr = xr2; xz = xz2; xn = xn2;
  }
}

// mem = bt + mem_f + mem_b
__global__ void memcomb(const float* __restrict__ memf, const float* __restrict__ memb,
                        const float* __restrict__ sutt, float* __restrict__ memm) {
  int idx = blockIdx.x * 256 + threadIdx.x;
  if (idx >= 40 * BM1 * 100) return;
  int j = idx % 100; int rem = idx / 100; int row = rem % BM1; int t = rem / BM1;
  float v = memf[idx] + memb[idx];
  int sidx = row + 1 - 40 + t;
  if (sidx >= 0) v += sutt[sidx * 100 + j];
  memm[idx] = v;
}

__global__ void epsinit(const float* __restrict__ sutt, float* __restrict__ eps) {
  int idx = blockIdx.x * 256 + threadIdx.x;
  if (idx < BM1 * 100) eps[idx] = sutt[idx + 100];
}

// attention scores + softmax -> gates + attn output (f32)
__global__ __launch_bounds__(64) void attnsc(const float* __restrict__ eps,
                                             const float* __restrict__ memm,
                                             float* __restrict__ gatesw,
                                             float* __restrict__ outat) {
  int row = blockIdx.x, k = threadIdx.x;
  __shared__ float el[100];
  for (int i = k; i < 100; i += 64) el[i] = eps[row * 100 + i];
  __syncthreads();
  float val = -INFINITY;
  if (k < 40) {
    if (row + 1 - 40 + k >= 0) {
      const float* mrow = memm + ((size_t)k * BM1 + row) * 100;
      float s = 0.f;
      for (int d = 0; d < 100; ++d) s += el[d] * mrow[d];
      val = s;
    } else val = -1e10f;
  }
  float mx = val;
  for (int off = 32; off > 0; off >>= 1) mx = fmaxf(mx, __shfl_xor(mx, off));
  float ex = (k < 40) ? expf(val - mx) : 0.f;
  float sm = ex;
  for (int off = 32; off > 0; off >>= 1) sm += __shfl_xor(sm, off);
  if (k < 40) {
    float sc = ex / sm;
    gatesw[k * BM1 + row] = sc;
    outat[row * 40 + k] = sc;
  }
}

// cr/cw precompute GEMM: grid (16, 40, 2)
__global__ __launch_bounds__(256) void crcw3(const float* __restrict__ memm,
                                             const float* __restrict__ Wr, const float* __restrict__ br,
                                             const float* __restrict__ Ww, const float* __restrict__ bw,
                                             float* __restrict__ crb, float* __restrict__ cwb) {
  __shared__ float ml[32][101];
  int tid = threadIdx.x;
  int rt = blockIdx.x * 32, t = blockIdx.y, which = blockIdx.z;
  for (int idx = tid; idx < 3200; idx += 256) {
    int r = idx / 100, k = idx - r * 100; int row = rt + r;
    ml[r][k] = (row < BM1) ? memm[((size_t)t * BM1 + row) * 100 + k] : 0.f;
  }
  __syncthreads();
  const float* Wm = which ? Ww : Wr;
  const float* bm = which ? bw : br;
  float* ob = which ? cwb : crb;
  for (int o = tid; o < 3200; o += 256) {
    int r = o & 31, hh = o >> 5;
    float acc = bm[hh];
    const float* wr = Wm + hh * 100;
    for (int k = 0; k < 100; ++k) acc += ml[r][k] * wr[k];
    int row = rt + r;
    if (row < BM1) ob[((size_t)t * BM1 + row) * 100 + hh] = acc;
  }
}

// ------------------------------------------------------------------
// AttnGRU scan v4 (validated r9)
// ------------------------------------------------------------------
struct Att4Args {
  const float* urT; const float* uT;
  const float* bur; const float* bu;
  const float* crb; const float* cwb;
  const float* gatesw; float* eps;
};

__global__ __launch_bounds__(512) void attscan4(Att4Args a) {
  __shared__ float UrT[10000];
  __shared__ float UT[10000];
  __shared__ float hl[2][4][104];
  int tid = threadIdx.x, rt = blockIdx.x * 4;
  for (int i = tid; i < 10000; i += 512) { UrT[i] = a.urT[i]; UT[i] = a.uT[i]; }
  for (int i = tid; i < 832; i += 512) ((float*)hl)[i] = 0.f;
  int r = tid / 100, j = tid - r * 100;
  int row = rt + r;
  bool act = (tid < 400) && (row < BM1);
  float cr = 0.f, cw = 0.f, gw = 0.f;
  if (act) {
    size_t ix = (size_t)row * 100 + j;
    cr = a.crb[ix]; cw = a.cwb[ix]; gw = a.gatesw[row];
  }
  float hprev = 0.f;
  __syncthreads();
  for (int t = 0; t < 40; ++t) {
    int nxt = (t + 1) & 1, cur = t & 1;
    float cr2 = 0.f, cw2 = 0.f, gw2 = 0.f;
    if (act && t < 39) {
      size_t ix = ((size_t)(t + 1) * BM1 + row) * 100 + j;
      cr2 = a.crb[ix]; cw2 = a.cwb[ix]; gw2 = a.gatesw[(t + 1) * BM1 + row];
    }
    float v = 0.f;
    if (act) {
      float hr = a.bur[j], hu = a.bu[j];
      const float* hrow = hl[cur][r];
      for (int k = 0; k < 100; ++k) {
        float hv = hrow[k];
        hr += hv * UrT[k * 100 + j];
        hu += hv * UT[k * 100 + j];
      }
      float rg_ = sigm(cr + hr);
      float ht = tanhf(cw + rg_ * hu);
      v = gw * ht + (1.f - gw) * hprev;
    }
    if (tid < 400) hl[nxt][r][j] = v;
    hprev = v;
    __syncthreads();
    cr = cr2; cw = cw2; gw = gw2;
  }
  if (act) a.eps[(size_t)row * 100 + j] += hprev;
}

// classifier -> f32
__global__ __launch_bounds__(64) void cls_k(const float* __restrict__ sutt,
                                            const float* __restrict__ eps,
                                            const float* __restrict__ cW, const float* __restrict__ cb,
                                            float* __restrict__ outp) {
  int b = blockIdx.x, j = threadIdx.x;
  __shared__ float sl[100];
  for (int i = j; i < 100; i += 64) sl[i] = (b == 0) ? sutt[i] : eps[(b - 1) * 100 + i];
  __syncthreads();
  float lg = -INFINITY;
  if (j < 7) {
    lg = cb[j];
    const float* wr = cW + j * 100;
    for (int k = 0; k < 100; ++k) lg += sl[k] * wr[k];
  }
  float mx = lg;
  for (int off = 32; off > 0; off >>= 1) mx = fmaxf(mx, __shfl_xor(mx, off));
  float ex = (j < 7) ? expf(lg - mx) : 0.f;
  float sm = ex;
  for (int off = 32; off > 0; off >>= 1) sm += __shfl_xor(sm, off);
  if (j < 7) outp[b * 7 + j] = lg - mx - logf(sm);
}

// ------------------------------------------------------------------
extern "C" void kernel_launch(void* const* d_in, const int* in_sizes, int n_in,
                              void* d_out, int out_size, void* d_ws, size_t ws_size,
                              hipStream_t stream) {
  (void)n_in; (void)out_size; (void)ws_size;

  bool sigOrder = (in_sizes[7] == 360000);   // r4 evidence: dict order

  const void *p_sents, *p_lens, *p_emb;
  const void *p_lWih_f, *p_lWhh_f, *p_lbih_f, *p_lbhh_f;
  const void *p_lWih_b, *p_lWhh_b, *p_lbih_b, *p_lbhh_b;
  const void *p_gWih_f, *p_gWhh_f, *p_gbih_f, *p_gbhh_f;
  const void *p_gWih_b, *p_gWhh_b, *p_gbih_b, *p_gbhh_b;
  const void *p_lin1W, *p_lin1b;
  const void *p_attWr, *p_attUr, *p_attW, *p_attU;
  const void *p_attbr, *p_attbur, *p_attbw, *p_attbu;
  const void *p_clsW, *p_clsb;

  p_sents = d_in[0]; p_lens = d_in[1]; p_emb = d_in[2];
  p_lWih_f = d_in[3]; p_lWhh_f = d_in[4]; p_lbih_f = d_in[5]; p_lbhh_f = d_in[6];
  if (sigOrder) {
    p_lWih_b = d_in[7];  p_lWhh_b = d_in[8];  p_lbih_b = d_in[9];  p_lbhh_b = d_in[10];
    p_lin1W  = d_in[11]; p_lin1b  = d_in[12];
    p_gWih_f = d_in[13]; p_gWhh_f = d_in[14]; p_gbih_f = d_in[15]; p_gbhh_f = d_in[16];
    p_gWih_b = d_in[17]; p_gWhh_b = d_in[18]; p_gbih_b = d_in[19]; p_gbhh_b = d_in[20];
    p_attWr  = d_in[21]; p_attbr  = d_in[22]; p_attUr  = d_in[23]; p_attbur = d_in[24];
    p_attW   = d_in[25]; p_attbw  = d_in[26]; p_attU   = d_in[27]; p_attbu  = d_in[28];
    p_clsW   = d_in[29]; p_clsb   = d_in[30];
  } else {
    p_gWih_f = d_in[7];  p_gWhh_f = d_in[8];  p_gbih_f = d_in[9];  p_gbhh_f = d_in[10];
    p_lWih_b = d_in[11]; p_lWhh_b = d_in[12]; p_lbih_b = d_in[13]; p_lbhh_b = d_in[14];
    p_gWih_b = d_in[15]; p_gWhh_b = d_in[16]; p_gbih_b = d_in[17]; p_gbhh_b = d_in[18];
    p_lin1W  = d_in[19]; p_lin1b  = d_in[20];
    p_attWr  = d_in[21]; p_attUr  = d_in[22]; p_attW   = d_in[23]; p_attU   = d_in[24];
    p_attbr  = d_in[25]; p_attbur = d_in[26]; p_attbw  = d_in[27]; p_attbu  = d_in[28];
    p_clsW   = d_in[29]; p_clsb   = d_in[30];
  }

  char* wp = (char*)d_ws;
  auto carve = [&](size_t bytes) {
    char* p = wp;
    wp += (bytes + 255) & ~(size_t)255;
    return p;
  };
  int*   flag  = (int*)  carve(256);
  int*   cnt   = (int*)  carve(256);
  float* allf  = (float*)carve((size_t)NF_TOT * 4);
  float* wt    = (float*)carve((size_t)120000 * 4);
  u16*   wL2   = (u16*)  carve((size_t)1536000 * 2);
  float* bsum  = (float*)carve((size_t)2400 * 4);
  float* hbufR = (float*)carve((size_t)2 * 2 * 512 * 320 * 4);
  float* maxb  = (float*)carve((size_t)B_SZ * 600 * 4);
  float* sutt  = (float*)carve((size_t)B_SZ * 100 * 4);
  // big region: xallR (32.8MB bf16, dead after lstm8) aliases xg+memf+memb
  size_t xg_sz   = (size_t)2 * 40 * BM1 * 300 * 4;
  size_t memf_sz = (size_t)40 * BM1 * 100 * 4;
  char*  big   = carve(xg_sz + 2 * memf_sz);
  u16*   xallR = (u16*)big;
  float* xg    = (float*)big;
  float* memf  = (float*)(big + xg_sz);
  float* memb  = (float*)(big + xg_sz + memf_sz);
  float* memm  = (float*)carve(memf_sz);
  float* gatesw= (float*)carve((size_t)40 * BM1 * 4);
  float* eps   = (float*)carve((size_t)BM1 * 100 * 4);
  float* crb   = xg;
  float* cwb   = xg + (size_t)40 * BM1 * 100;

  float* out_pred = (float*)d_out;
  float* out_attn = out_pred + (size_t)B_SZ * NC_;

  detect_k<<<1, 256, 0, stream>>>((const u32*)p_emb, flag);

  NormFArgs nf;
  {
    const void* srcs[NF_NSEG] = {
      p_lWih_f, p_lWhh_f, p_lWih_b, p_lWhh_b,
      p_lbih_f, p_lbhh_f, p_lbih_b, p_lbhh_b,
      p_gWih_f, p_gWhh_f, p_gbih_f, p_gbhh_f,
      p_gWih_b, p_gWhh_b, p_gbih_b, p_gbhh_b,
      p_lin1W,  p_lin1b,
      p_attWr,  p_attUr,  p_attW,   p_attU,
      p_attbr,  p_attbur, p_attbw,  p_attbu,
      p_clsW,   p_clsb };
    for (int i = 0; i < NF_NSEG; ++i) nf.src[i] = srcs[i];
    nf.flag = flag; nf.dst = allf;
  }
  norm_f32<<<2048, 256, 0, stream>>>(nf);
  transp_k<<<(120000 + 255) / 256, 256, 0, stream>>>(allf, wt);
  tr_lstm2<<<(1538400 + 255) / 256, 256, 0, stream>>>(allf, wL2, bsum);
  xgat2<<<dim3(8, 100), 256, 0, stream>>>((const int*)p_sents, p_emb, flag, xallR);

  hipMemsetAsync(cnt, 0, 256, stream);
  hipMemsetAsync(hbufR, 0, (size_t)2 * 2 * 512 * 320 * 4, stream);

  Lstm8Args la;
  la.lens = (const int*)p_lens;
  la.xallR = xallR; la.wL2 = wL2; la.bsum = bsum;
  la.hbufR = hbufR; la.maxb = maxb; la.cnt = cnt;
  lstm8<<<dim3(4, 15, 2), 512, 0, stream>>>(la);

  sutt_k<<<512, 128, 0, stream>>>(maxb, allf + AF_LIN1W, allf + AF_LIN1B, sutt);

  gxg3<<<dim3(16, 40, 2), 256, 0, stream>>>(sutt,
      allf + AF_GWIH_F, allf + AF_GBIH_F,
      allf + AF_GWIH_B, allf + AF_GBIH_B, xg);

  Gru4Args ga;
  ga.wt = wt;
  ga.bhh[0] = allf + AF_GBHH_F; ga.bhh[1] = allf + AF_GBHH_B;
  ga.xg = xg; ga.memf = memf; ga.memb = memb;
  gru4<<<dim3(128, 2), 512, 0, stream>>>(ga);

  memcomb<<<(40 * BM1 * 100 + 255) / 256, 256, 0, stream>>>(memf, memb, sutt, memm);
  epsinit<<<(BM1 * 100 + 255) / 256, 256, 0, stream>>>(sutt, eps);

  for (int hop = 0; hop < NHOP; ++hop) {
    attnsc<<<BM1, 64, 0, stream>>>(eps, memm, gatesw, out_attn + (size_t)hop * BM1 * 40);
    crcw3<<<dim3(16, 40, 2), 256, 0, stream>>>(memm,
        allf + AF_ATTWR + hop * 10000, allf + AF_ATTBR + hop * 100,
        allf + AF_ATTW  + hop * 10000, allf + AF_ATTBW + hop * 100, crb, cwb);
    Att4Args aa;
    aa.urT = wt + 60000 + hop * 10000;
    aa.uT  = wt + 90000 + hop * 10000;
    aa.bur = allf + AF_ATTBUR + hop * 100;
    aa.bu  = allf + AF_ATTBU  + hop * 100;
    aa.crb = crb; aa.cwb = cwb;
    aa.gatesw = gatesw; aa.eps = eps;
    attscan4<<<128, 512, 0, stream>>>(aa);
  }

  cls_k<<<512, 64, 0, stream>>>(sutt, eps, allf + AF_CLSW, allf + AF_CLSB, out_pred);
}